// Round 14
// baseline (449.570 us; speedup 1.0000x reference)
//
#include <hip/hip_runtime.h>
#include <cstdint>
#include <cstddef>

#define D 128
#define DDEC 512

typedef __attribute__((ext_vector_type(8))) short short8;
typedef __attribute__((ext_vector_type(4))) float f32x4;

__device__ __forceinline__ ushort f2bf(float f) {
  uint32_t u = __float_as_uint(f);
  u = u + 0x7FFF + ((u >> 16) & 1);   // round-to-nearest-even
  return (ushort)(u >> 16);
}
__device__ __forceinline__ float bf2f(ushort u) {
  return __uint_as_float(((uint32_t)u) << 16);
}

// ---------------------------------------------------------------- detect int64 layout
__global__ void detect_i64(const int* __restrict__ ei, int* __restrict__ flag) {
  if (threadIdx.x == 0 && blockIdx.x == 0) {
    int allz = 1;
    for (int k = 0; k < 64; ++k)
      if (ei[2 * k + 1] != 0) { allz = 0; break; }
    *flag = allz ? 2 : 1;  // 2 => int64 storage read as int32 pairs
  }
}

// ---------------------------------------------------------------- prep: xcvt (+tgt) + wcvt + count_deg
__global__ __launch_bounds__(256) void prep_count_kernel(
    const float* __restrict__ x, const float* __restrict__ Wl,
    const float* __restrict__ Wr, const float* __restrict__ Wp,
    const float* __restrict__ Wd1, const float* __restrict__ Wd2,
    const int* __restrict__ ei,
    ushort* __restrict__ xb, ushort* __restrict__ wb,
    float* __restrict__ tgt,   // may be null
    int* __restrict__ deg, const int* __restrict__ flag,
    int n8, int xblocks, int E)
{
  int b = blockIdx.x;
  if (b < xblocks) {
    int i = b * 256 + threadIdx.x;
    if (i >= n8) return;
    const float* s = x + (size_t)i * 8;
    float4 f0 = *(const float4*)s;
    float4 f1 = *(const float4*)(s + 4);
    short8 v;
    v[0] = (short)f2bf(f0.x); v[1] = (short)f2bf(f0.y);
    v[2] = (short)f2bf(f0.z); v[3] = (short)f2bf(f0.w);
    v[4] = (short)f2bf(f1.x); v[5] = (short)f2bf(f1.y);
    v[6] = (short)f2bf(f1.z); v[7] = (short)f2bf(f1.w);
    *(short8*)&xb[(size_t)i * 8] = v;
    if (tgt) {
      *(float4*)&tgt[(size_t)i * 8] = f0;
      *(float4*)&tgt[(size_t)i * 8 + 4] = f1;
    }
  } else if (b < xblocks + 704) {
    int i = (b - xblocks) * 256 + threadIdx.x;
    if (i >= 180224) return;
    float v;
    if (i < 16384) v = Wl[i];
    else if (i < 32768) v = Wr[i - 16384];
    else if (i < 49152) v = Wp[i - 32768];
    else if (i < 114688) v = Wd1[i - 49152];
    else v = Wd2[i - 114688];
    wb[i] = f2bf(v);
  } else {
    int e = (b - xblocks - 704) * 256 + threadIdx.x;
    if (e >= E) return;
    int s = *flag;
    int dst = ei[((long long)E + e) * s];
    atomicAdd(&deg[dst], 1);
  }
}

// ---------------------------------------------------------------- CSR scan + fill
__global__ __launch_bounds__(256) void scan_reduce(
    const int* __restrict__ deg, int* __restrict__ bsum, int N)
{
  __shared__ int red[256];
  int base = blockIdx.x * 1024 + threadIdx.x * 4;
  int s = 0;
#pragma unroll
  for (int k = 0; k < 4; ++k) { int i = base + k; if (i < N) s += deg[i]; }
  red[threadIdx.x] = s;
  __syncthreads();
  for (int off = 128; off > 0; off >>= 1) {
    if (threadIdx.x < off) red[threadIdx.x] += red[threadIdx.x + off];
    __syncthreads();
  }
  if (threadIdx.x == 0) bsum[blockIdx.x] = red[0];
}

__global__ void scan_bsum(int* __restrict__ bsum, int* __restrict__ rowptr,
                          int NB, int N, int E)
{
  __shared__ int tmp[256];
  int t = threadIdx.x;
  int v = (t < NB) ? bsum[t] : 0;
  tmp[t] = v;
  __syncthreads();
  for (int off = 1; off < 256; off <<= 1) {
    int add = (t >= off) ? tmp[t - off] : 0;
    __syncthreads();
    tmp[t] += add;
    __syncthreads();
  }
  if (t < NB) bsum[t] = tmp[t] - v;  // exclusive
  if (t == 0) rowptr[N] = E;
}

__global__ __launch_bounds__(256) void scan_final(
    const int* __restrict__ deg, const int* __restrict__ bsum,
    int* __restrict__ rowptr, int N)
{
  __shared__ int tsum[256];
  int base = blockIdx.x * 1024 + threadIdx.x * 4;
  int loc[4]; int s = 0;
#pragma unroll
  for (int k = 0; k < 4; ++k) { int i = base + k; loc[k] = (i < N) ? deg[i] : 0; s += loc[k]; }
  tsum[threadIdx.x] = s;
  __syncthreads();
  for (int off = 1; off < 256; off <<= 1) {
    int add = (threadIdx.x >= off) ? tsum[threadIdx.x - off] : 0;
    __syncthreads();
    tsum[threadIdx.x] += add;
    __syncthreads();
  }
  int excl = tsum[threadIdx.x] - s + bsum[blockIdx.x];
#pragma unroll
  for (int k = 0; k < 4; ++k) {
    int i = base + k;
    if (i < N) { rowptr[i] = excl; excl += loc[k]; }
  }
}

__global__ __launch_bounds__(256) void fill_csr(
    const int* __restrict__ ei, const int* __restrict__ rowptr,
    int* __restrict__ fillc, int* __restrict__ colidx,
    const int* __restrict__ flag, int E)
{
  int e = blockIdx.x * 256 + threadIdx.x;
  if (e >= E) return;
  int s = *flag;
  int src = ei[(long long)e * s];
  int dst = ei[((long long)E + e) * s];
  int pos = rowptr[dst] + atomicAdd(&fillc[dst], 1);
  colidx[pos] = src;
}

// ---------------------------------------------------------------- gather-mean (bf16)
__global__ __launch_bounds__(256) void aggregate_kernel(
    const int* __restrict__ rowptr, const int* __restrict__ colidx,
    const ushort* __restrict__ xb, ushort* __restrict__ aggrb, int N)
{
  int wave = (blockIdx.x * 256 + threadIdx.x) >> 6;
  int lane = threadIdx.x & 63;
  if (wave >= N) return;
  int s = rowptr[wave], epos = rowptr[wave + 1];
  float ax = 0.f, ay = 0.f;
  int e = s;
  for (; e + 3 < epos; e += 4) {
    int s0 = colidx[e], s1 = colidx[e + 1], s2 = colidx[e + 2], s3 = colidx[e + 3];
    uint u0 = *(const uint*)&xb[(size_t)s0 * D + lane * 2];
    uint u1 = *(const uint*)&xb[(size_t)s1 * D + lane * 2];
    uint u2 = *(const uint*)&xb[(size_t)s2 * D + lane * 2];
    uint u3 = *(const uint*)&xb[(size_t)s3 * D + lane * 2];
    ax += __uint_as_float(u0 << 16) + __uint_as_float(u1 << 16)
        + __uint_as_float(u2 << 16) + __uint_as_float(u3 << 16);
    ay += __uint_as_float(u0 & 0xFFFF0000u) + __uint_as_float(u1 & 0xFFFF0000u)
        + __uint_as_float(u2 & 0xFFFF0000u) + __uint_as_float(u3 & 0xFFFF0000u);
  }
  for (; e < epos; ++e) {
    uint u0 = *(const uint*)&xb[(size_t)colidx[e] * D + lane * 2];
    ax += __uint_as_float(u0 << 16);
    ay += __uint_as_float(u0 & 0xFFFF0000u);
  }
  int degn = epos - s;
  float inv = 1.0f / (float)(degn > 0 ? degn : 1);
  uint out = ((uint)f2bf(ax * inv)) | (((uint)f2bf(ay * inv)) << 16);
  *(uint*)&aggrb[(size_t)wave * D + lane * 2] = out;
}

// ---------------------------------------------------------------- MFMA helpers
__device__ __forceinline__ void mma_tile_g(const ushort* __restrict__ A, size_t ald,
                                           const ushort* __restrict__ B, size_t bld,
                                           f32x4 acc[4][4], int lane)
{
  const int r = lane & 15, g = lane >> 4;
#pragma unroll
  for (int ks = 0; ks < 4; ++ks) {
    short8 a[4], b[4];
#pragma unroll
    for (int m = 0; m < 4; ++m)
      a[m] = *(const short8*)&A[(size_t)(m * 16 + r) * ald + ks * 32 + g * 8];
#pragma unroll
    for (int n = 0; n < 4; ++n)
      b[n] = *(const short8*)&B[(size_t)(n * 16 + r) * bld + ks * 32 + g * 8];
#pragma unroll
    for (int m = 0; m < 4; ++m)
#pragma unroll
      for (int n = 0; n < 4; ++n)
        acc[m][n] = __builtin_amdgcn_mfma_f32_16x16x32_bf16(a[m], b[n], acc[m][n], 0, 0, 0);
  }
}

__device__ __forceinline__ void mma_tile_l(const ushort* aLds,
                                           const ushort* __restrict__ bGlb, size_t bld,
                                           f32x4 acc[4][4], int lane)
{
  const int r = lane & 15, g = lane >> 4;
#pragma unroll
  for (int ks = 0; ks < 4; ++ks) {
    short8 a[4], b[4];
#pragma unroll
    for (int m = 0; m < 4; ++m)
      a[m] = *(const short8*)&aLds[(m * 16 + r) * 136 + ks * 32 + g * 8];
#pragma unroll
    for (int n = 0; n < 4; ++n)
      b[n] = *(const short8*)&bGlb[(size_t)(n * 16 + r) * bld + ks * 32 + g * 8];
#pragma unroll
    for (int m = 0; m < 4; ++m)
#pragma unroll
      for (int n = 0; n < 4; ++n)
        acc[m][n] = __builtin_amdgcn_mfma_f32_16x16x32_bf16(a[m], b[n], acc[m][n], 0, 0, 0);
  }
}

// swapped-operand variant: out-col gets the (g*4+reg) mapping -> float4 stores
__device__ __forceinline__ void mma_tile_l_T(const ushort* aLds,
                                             const ushort* __restrict__ bGlb, size_t bld,
                                             f32x4 acc[4][4], int lane)
{
  const int r = lane & 15, g = lane >> 4;
#pragma unroll
  for (int ks = 0; ks < 4; ++ks) {
    short8 a[4], b[4];
#pragma unroll
    for (int m = 0; m < 4; ++m)
      a[m] = *(const short8*)&aLds[(m * 16 + r) * 136 + ks * 32 + g * 8];
#pragma unroll
    for (int n = 0; n < 4; ++n)
      b[n] = *(const short8*)&bGlb[(size_t)(n * 16 + r) * bld + ks * 32 + g * 8];
#pragma unroll
    for (int m = 0; m < 4; ++m)
#pragma unroll
      for (int n = 0; n < 4; ++n)
        acc[m][n] = __builtin_amdgcn_mfma_f32_16x16x32_bf16(b[n], a[m], acc[m][n], 0, 0, 0);
  }
}

// stage 128x128 f32 -> LDS bf16 [128][136] (fallback gemm_z only)
__device__ __forceinline__ void stage128(const float* __restrict__ src, int N,
                                         int row0, ushort* lds, int t)
{
#pragma unroll
  for (int p = 0; p < 8; ++p) {
    int r = (t >> 4) + p * 16;
    int c = (t & 15) * 8;
    short8 v = {};
    int row = row0 + r;
    if (row < N) {
      const float* s = src + (size_t)row * D + c;
      float4 f0 = *(const float4*)s;
      float4 f1 = *(const float4*)(s + 4);
      v[0] = (short)f2bf(f0.x); v[1] = (short)f2bf(f0.y);
      v[2] = (short)f2bf(f0.z); v[3] = (short)f2bf(f0.w);
      v[4] = (short)f2bf(f1.x); v[5] = (short)f2bf(f1.y);
      v[6] = (short)f2bf(f1.z); v[7] = (short)f2bf(f1.w);
    }
    *(short8*)&lds[r * 136 + c] = v;
  }
}

// ------------------------------------------------- FUSED: h-GEMM + z-GEMM + BN stats
// stats: in-wave shfl reduce over g + small LDS wm-pair exchange -> 4 blocks/CU
__global__ __launch_bounds__(256, 4) void gemm_hz_dstat(
    const ushort* __restrict__ aggrb, const ushort* __restrict__ xb,
    const ushort* __restrict__ Wlb, const ushort* __restrict__ Wrb,
    const ushort* __restrict__ Wpb, const ushort* __restrict__ Wd1b,
    const float* __restrict__ bl, const float* __restrict__ bp,
    const float* __restrict__ ap,
    float* __restrict__ h, ushort* __restrict__ hb, float* __restrict__ z,
    float* __restrict__ sums, float* __restrict__ sumsq, int N)
{
  __shared__ ushort Hs[128 * 136];
  __shared__ float sp[2][2][2][4][16];  // [pb][stat][wn][n][col16] = 4KB
  const int t = threadIdx.x;
  const int row0 = blockIdx.x * 128;
  const int lane = t & 63, w = t >> 6;
  const int wm = w >> 1, wn = w & 1;
  const int g = lane >> 4, cr = lane & 15;
  // ---- h = leaky(aggr@Wl^T + bl + x@Wr^T, 0.5) -> Hs only
  {
    f32x4 acc[4][4] = {};
    mma_tile_g(aggrb + (size_t)(row0 + wm * 64) * D, D, Wlb + (size_t)(wn * 64) * D, D, acc, lane);
    mma_tile_g(xb + (size_t)(row0 + wm * 64) * D, D, Wrb + (size_t)(wn * 64) * D, D, acc, lane);
#pragma unroll
    for (int n = 0; n < 4; ++n) {
      int col = wn * 64 + n * 16 + cr;
      float b = bl[col];
#pragma unroll
      for (int m = 0; m < 4; ++m)
#pragma unroll
        for (int rr = 0; rr < 4; ++rr) {
          int lrow = wm * 64 + m * 16 + g * 4 + rr;
          float v = acc[m][n][rr] + b;
          v = (v >= 0.f) ? v : 0.5f * v;
          Hs[lrow * 136 + col] = f2bf(v);
        }
    }
  }
  __syncthreads();
  // ---- cooperative vectorized h (f32 from bf16) + hb stores
#pragma unroll
  for (int p = 0; p < 8; ++p) {
    int idx = t + p * 256;
    int r = idx >> 4, c = (idx & 15) * 8;
    int row = row0 + r;
    if (row < N) {
      short8 v = *(short8*)&Hs[r * 136 + c];
      *(short8*)&hb[(size_t)row * D + c] = v;
      float4 f0, f1;
      f0.x = bf2f((ushort)v[0]); f0.y = bf2f((ushort)v[1]);
      f0.z = bf2f((ushort)v[2]); f0.w = bf2f((ushort)v[3]);
      f1.x = bf2f((ushort)v[4]); f1.y = bf2f((ushort)v[5]);
      f1.z = bf2f((ushort)v[6]); f1.w = bf2f((ushort)v[7]);
      *(float4*)&h[(size_t)row * D + c] = f0;
      *(float4*)&h[(size_t)row * D + c + 4] = f1;
    }
  }
  // ---- z = prelu(Hs@Wp^T + bp, a): transposed orientation -> float4 stores
  {
    f32x4 zacc[4][4] = {};
    mma_tile_l_T(Hs + wm * 64 * 136, Wpb + (size_t)(wn * 64) * D, D, zacc, lane);
    const float alpha = ap[0];
#pragma unroll
    for (int m = 0; m < 4; ++m) {
      int row = row0 + wm * 64 + m * 16 + cr;
      if (row < N) {
#pragma unroll
        for (int n = 0; n < 4; ++n) {
          int col = wn * 64 + n * 16 + g * 4;
          float4 bv = *(const float4*)&bp[col];
          float4 o;
          float v0 = zacc[m][n][0] + bv.x; o.x = (v0 >= 0.f) ? v0 : alpha * v0;
          float v1 = zacc[m][n][1] + bv.y; o.y = (v1 >= 0.f) ? v1 : alpha * v1;
          float v2 = zacc[m][n][2] + bv.z; o.z = (v2 >= 0.f) ? v2 : alpha * v2;
          float v3 = zacc[m][n][3] + bv.w; o.w = (v3 >= 0.f) ? v3 : alpha * v3;
          *(float4*)&z[(size_t)row * D + col] = o;
        }
      }
    }
  }
  // ---- BN stats of mm = Hs@Wd1^T (bd1 cancels); shfl over g + wm-pair LDS exchange
  for (int cc = 0; cc < 4; ++cc) {
    int c0 = cc * 128;
    int pb = cc & 1;
    f32x4 dacc[4][4] = {};
    mma_tile_l(Hs + wm * 64 * 136, Wd1b + (size_t)(c0 + wn * 64) * D, D, dacc, lane);
    float ss1[4], ss2[4];
#pragma unroll
    for (int n = 0; n < 4; ++n) {
      float s1 = 0.f, s2 = 0.f;
#pragma unroll
      for (int m = 0; m < 4; ++m)
#pragma unroll
        for (int rr = 0; rr < 4; ++rr) {
          int row = row0 + wm * 64 + m * 16 + g * 4 + rr;
          if (row < N) {
            float v = dacc[m][n][rr];
            s1 += v; s2 += v * v;
          }
        }
      s1 += __shfl_xor(s1, 16); s1 += __shfl_xor(s1, 32);
      s2 += __shfl_xor(s2, 16); s2 += __shfl_xor(s2, 32);
      ss1[n] = s1; ss2[n] = s2;
    }
    if (wm == 1 && lane < 16) {
#pragma unroll
      for (int n = 0; n < 4; ++n) {
        sp[pb][0][wn][n][lane] = ss1[n];
        sp[pb][1][wn][n][lane] = ss2[n];
      }
    }
    __syncthreads();
    if (wm == 0 && lane < 16) {
#pragma unroll
      for (int n = 0; n < 4; ++n) {
        int col = c0 + wn * 64 + n * 16 + lane;
        atomicAdd(&sums[col], ss1[n] + sp[pb][0][wn][n][lane]);
        atomicAdd(&sumsq[col], ss2[n] + sp[pb][1][wn][n][lane]);
      }
    }
  }
}

// mm-stats -> affine: scale = g*rsqrt(var+eps), shift = beta - mu*scale (bd1 cancels)
__global__ void finalize_kernel(
    const float* __restrict__ sums, const float* __restrict__ sumsq,
    const float* __restrict__ gamma, const float* __restrict__ beta,
    float* __restrict__ scale, float* __restrict__ shift, int N)
{
  int c = blockIdx.x * blockDim.x + threadIdx.x;
  if (c < DDEC) {
    float inv_n = 1.0f / (float)N;
    float mu = sums[c] * inv_n;
    float var = sumsq[c] * inv_n - mu * mu;
    float sc = gamma[c] * rsqrtf(var + 1e-5f);
    scale[c] = sc;
    shift[c] = beta[c] - mu * sc;
  }
}

// ------------------------------------------------- rec_v4: wave-private K-split, static indexing
// Wave (wm,wn): 64 rows x 64 c-cols per chunk; GEMM1->BN->private Dn->GEMM2 partial acc[4][8].
// No in-loop barriers. Cross-wn partials merged once via LDS dump (wn1 -> wn0).
__global__ __launch_bounds__(256, 2) void rec_v4(
    const ushort* __restrict__ hb, const ushort* __restrict__ Wd1b,
    const ushort* __restrict__ Wd2b,
    const float* __restrict__ scale, const float* __restrict__ shift,
    const float* __restrict__ bd2, float* __restrict__ rec, int N)
{
  __shared__ __align__(16) char smem[71680];  // Hs 34816 + 4x Dn 9216; dump reuses 65536
  ushort* Hs = (ushort*)smem;                 // [128][136]
  const int t = threadIdx.x;
  const int row0 = blockIdx.x * 128;
#pragma unroll
  for (int p = 0; p < 8; ++p) {
    int idx = t + p * 256;
    int r0 = idx >> 4, c = (idx & 15) * 8;
    short8 v = *(const short8*)&hb[(size_t)(row0 + r0) * D + c];
    *(short8*)&Hs[r0 * 136 + c] = v;
  }
  __syncthreads();
  const int lane = t & 63, w = t >> 6;
  const int wm = w >> 1, wn = w & 1;
  const int r = lane & 15, g = lane >> 4;
  ushort* Dn = (ushort*)(smem + 34816) + w * (64 * 72);  // private [64][72]
  const ushort* Arow = Hs + wm * 64 * 136;
  f32x4 acc[4][8] = {};
  for (int cc = 0; cc < 4; ++cc) {
    const int c0 = cc * 128 + wn * 64;   // this wave's 64 c-columns
    // GEMM1: 64 rows x 64 cols, K=128
    f32x4 dacc[4][4] = {};
#pragma unroll
    for (int ks = 0; ks < 4; ++ks) {
      short8 a[4], b[4];
#pragma unroll
      for (int m = 0; m < 4; ++m)
        a[m] = *(const short8*)&Arow[(m * 16 + r) * 136 + ks * 32 + g * 8];
#pragma unroll
      for (int n = 0; n < 4; ++n)
        b[n] = *(const short8*)&Wd1b[(size_t)(c0 + n * 16 + r) * D + ks * 32 + g * 8];
#pragma unroll
      for (int m = 0; m < 4; ++m)
#pragma unroll
        for (int n = 0; n < 4; ++n)
          dacc[m][n] = __builtin_amdgcn_mfma_f32_16x16x32_bf16(a[m], b[n], dacc[m][n], 0, 0, 0);
    }
    // BN + leaky -> private Dn (same-wave LDS ordering; no barrier)
#pragma unroll
    for (int n = 0; n < 4; ++n) {
      int cg = c0 + n * 16 + r;
      float sc = scale[cg], sh = shift[cg];
#pragma unroll
      for (int m = 0; m < 4; ++m)
#pragma unroll
        for (int rr = 0; rr < 4; ++rr) {
          float v = dacc[m][n][rr] * sc + sh;
          v = (v >= 0.f) ? v : 0.01f * v;
          Dn[(m * 16 + g * 4 + rr) * 72 + n * 16 + r] = f2bf(v);
        }
    }
    // GEMM2 partial: acc += Dn(64x64) @ Wd2[:, c0..c0+64]^T over all 128 out cols
#pragma unroll
    for (int ks2 = 0; ks2 < 2; ++ks2) {
      short8 a2[4];
#pragma unroll
      for (int m = 0; m < 4; ++m)
        a2[m] = *(const short8*)&Dn[(m * 16 + r) * 72 + ks2 * 32 + g * 8];
#pragma unroll
      for (int n8 = 0; n8 < 8; ++n8) {
        short8 b2 = *(const short8*)&Wd2b[(size_t)(n8 * 16 + r) * DDEC + c0 + ks2 * 32 + g * 8];
#pragma unroll
        for (int m = 0; m < 4; ++m)
          acc[m][n8] = __builtin_amdgcn_mfma_f32_16x16x32_bf16(b2, a2[m], acc[m][n8], 0, 0, 0);
      }
    }
  }
  __syncthreads();  // compute done; repurpose LDS for dump
  float* dump = (float*)smem + wm * 8192;  // 32KB per wm half
  if (wn == 1) {
#pragma unroll
    for (int m = 0; m < 4; ++m)
#pragma unroll
      for (int n8 = 0; n8 < 8; ++n8) {
        float4 o;
        o.x = acc[m][n8][0]; o.y = acc[m][n8][1];
        o.z = acc[m][n8][2]; o.w = acc[m][n8][3];
        *(float4*)&dump[(m * 8 + n8) * 256 + lane * 4] = o;
      }
  }
  __syncthreads();
  if (wn == 0) {
#pragma unroll
    for (int m = 0; m < 4; ++m) {
      int row = row0 + wm * 64 + m * 16 + r;
      if (row < N) {
#pragma unroll
        for (int n8 = 0; n8 < 8; ++n8) {
          int col = n8 * 16 + g * 4;
          float4 bv = *(const float4*)&bd2[col];
          float4 pd = *(const float4*)&dump[(m * 8 + n8) * 256 + lane * 4];
          float4 o;
          o.x = acc[m][n8][0] + pd.x + bv.x;
          o.y = acc[m][n8][1] + pd.y + bv.y;
          o.z = acc[m][n8][2] + pd.z + bv.z;
          o.w = acc[m][n8][3] + pd.w + bv.w;
          *(float4*)&rec[(size_t)row * D + col] = o;
        }
      }
    }
  }
}

// ------------------------------------------------- fallback kernels (non-ws path)
__global__ __launch_bounds__(256, 3) void gemm_h_mfma(
    const ushort* __restrict__ aggrb, const ushort* __restrict__ xb,
    const ushort* __restrict__ Wlb, const ushort* __restrict__ Wrb,
    const float* __restrict__ bl, float* __restrict__ h,
    ushort* __restrict__ hb, int N)
{
  const int t = threadIdx.x;
  const int row0 = blockIdx.x * 128;
  const int lane = t & 63, w = t >> 6;
  const int wm = w >> 1, wn = w & 1;
  f32x4 acc[4][4] = {};
  mma_tile_g(aggrb + (size_t)(row0 + wm * 64) * D, D, Wlb + (size_t)(wn * 64) * D, D, acc, lane);
  mma_tile_g(xb + (size_t)(row0 + wm * 64) * D, D, Wrb + (size_t)(wn * 64) * D, D, acc, lane);
  const int g = lane >> 4, cr = lane & 15;
#pragma unroll
  for (int n = 0; n < 4; ++n) {
    int col = wn * 64 + n * 16 + cr;
    float b = bl[col];
#pragma unroll
    for (int m = 0; m < 4; ++m)
#pragma unroll
      for (int rr = 0; rr < 4; ++rr) {
        int row = row0 + wm * 64 + m * 16 + g * 4 + rr;
        if (row < N) {
          float v = acc[m][n][rr] + b;
          v = (v >= 0.f) ? v : 0.5f * v;
          h[(size_t)row * D + col] = v;
          hb[(size_t)row * D + col] = f2bf(v);
        }
      }
  }
}

__global__ __launch_bounds__(256, 4) void dstat_mfma(
    const ushort* __restrict__ hb, const ushort* __restrict__ Wd1b,
    float* __restrict__ sums, float* __restrict__ sumsq, int N)
{
  __shared__ float part1[8][132];
  __shared__ float part2[8][132];
  const int t = threadIdx.x;
  const int row0 = blockIdx.x * 128;
  const int lane = t & 63, w = t >> 6;
  const int wm = w >> 1, wn = w & 1;
  const int g = lane >> 4, cr = lane & 15;
  for (int c0 = 0; c0 < DDEC; c0 += 128) {
    f32x4 dacc[4][4] = {};
    mma_tile_g(hb + (size_t)(row0 + wm * 64) * D, D,
               Wd1b + (size_t)(c0 + wn * 64) * D, D, dacc, lane);
#pragma unroll
    for (int n = 0; n < 4; ++n) {
      float s1 = 0.f, s2 = 0.f;
#pragma unroll
      for (int m = 0; m < 4; ++m)
#pragma unroll
        for (int rr = 0; rr < 4; ++rr) {
          int row = row0 + wm * 64 + m * 16 + g * 4 + rr;
          if (row < N) {
            float v = dacc[m][n][rr];
            s1 += v; s2 += v * v;
          }
        }
      part1[wm * 4 + g][wn * 64 + n * 16 + cr] = s1;
      part2[wm * 4 + g][wn * 64 + n * 16 + cr] = s2;
    }
    __syncthreads();
    if (t < 128) {
      float s = 0;
#pragma unroll
      for (int k = 0; k < 8; ++k) s += part1[k][t];
      atomicAdd(&sums[c0 + t], s);
    } else {
      int c = t - 128;
      float s = 0;
#pragma unroll
      for (int k = 0; k < 8; ++k) s += part2[k][c];
      atomicAdd(&sumsq[c0 + c], s);
    }
    __syncthreads();
  }
}

__global__ __launch_bounds__(256, 2) void rec_mfma_fb(
    const ushort* __restrict__ hb, const ushort* __restrict__ Wd1b,
    const ushort* __restrict__ Wd2b,
    const float* __restrict__ scale, const float* __restrict__ shift,
    const float* __restrict__ bd2, float* __restrict__ rec, int N)
{
  __shared__ ushort Hs[128 * 136];
  __shared__ ushort Dn[128 * 136];
  const int t = threadIdx.x;
  const int row0 = blockIdx.x * 128;
#pragma unroll
  for (int p = 0; p < 8; ++p) {
    int idx = t + p * 256;
    int r = idx >> 4, c = (idx & 15) * 8;
    short8 v = *(const short8*)&hb[(size_t)(row0 + r) * D + c];
    *(short8*)&Hs[r * 136 + c] = v;
  }
  const int lane = t & 63, w = t >> 6;
  const int wm = w >> 1, wn = w & 1;
  const int g = lane >> 4, cr = lane & 15;
  f32x4 acc[4][4] = {};
  __syncthreads();
  for (int c0 = 0; c0 < DDEC; c0 += 128) {
    f32x4 dacc[4][4] = {};
    mma_tile_l(Hs + wm * 64 * 136, Wd1b + (size_t)(c0 + wn * 64) * D, D, dacc, lane);
    __syncthreads();
#pragma unroll
    for (int n = 0; n < 4; ++n) {
      int lc = wn * 64 + n * 16 + cr;
      int c = c0 + lc;
      float sc = scale[c], sh = shift[c];
#pragma unroll
      for (int m = 0; m < 4; ++m)
#pragma unroll
        for (int rr = 0; rr < 4; ++rr) {
          float v = dacc[m][n][rr] * sc + sh;
          v = (v >= 0.f) ? v : 0.01f * v;
          Dn[(wm * 64 + m * 16 + g * 4 + rr) * 136 + lc] = f2bf(v);
        }
    }
    __syncthreads();
    mma_tile_l(Dn + wm * 64 * 136, Wd2b + (size_t)(wn * 64) * DDEC + c0, DDEC, acc, lane);
  }
#pragma unroll
  for (int n = 0; n < 4; ++n) {
    int col = wn * 64 + n * 16 + cr;
    float b = bd2[col];
#pragma unroll
    for (int m = 0; m < 4; ++m)
#pragma unroll
      for (int rr = 0; rr < 4; ++rr) {
        int row = row0 + wm * 64 + m * 16 + g * 4 + rr;
        if (row < N) rec[(size_t)row * D + col] = acc[m][n][rr] + b;
      }
  }
}

__global__ __launch_bounds__(256, 2) void gemm_z_staged(
    const float* __restrict__ h, const ushort* __restrict__ Wpb,
    const float* __restrict__ bp, const float* __restrict__ ap,
    float* __restrict__ z, int N)
{
  __shared__ ushort As[128 * 136];
  const int t = threadIdx.x;
  const int row0 = blockIdx.x * 128;
  stage128(h, N, row0, As, t);
  __syncthreads();
  const int lane = t & 63, w = t >> 6;
  const int wm = w >> 1, wn = w & 1;
  f32x4 acc[4][4] = {};
  mma_tile_l(As + wm * 64 * 136, Wpb + (size_t)(wn * 64) * D, D, acc, lane);
  const float alpha = ap[0];
  const int g = lane >> 4, cr = lane & 15;
#pragma unroll
  for (int n = 0; n < 4; ++n) {
    int col = wn * 64 + n * 16 + cr;
    float b = bp[col];
#pragma unroll
    for (int m = 0; m < 4; ++m)
#pragma unroll
      for (int rr = 0; rr < 4; ++rr) {
        int row = row0 + wm * 64 + m * 16 + g * 4 + rr;
        if (row < N) {
          float v = acc[m][n][rr] + b;
          z[(size_t)row * D + col] = (v >= 0.f) ? v : alpha * v;
        }
      }
  }
}

// ---------------------------------------------------------------- launch
extern "C" void kernel_launch(void* const* d_in, const int* in_sizes, int n_in,
                              void* d_out, int out_size, void* d_ws, size_t ws_size,
                              hipStream_t stream)
{
  const float* x   = (const float*)d_in[0];
  const int*   ei  = (const int*)d_in[1];
  const float* Wl  = (const float*)d_in[2];
  const float* bl  = (const float*)d_in[3];
  const float* Wr  = (const float*)d_in[4];
  const float* Wp  = (const float*)d_in[5];
  const float* bp  = (const float*)d_in[6];
  const float* ap  = (const float*)d_in[7];
  const float* Wd1 = (const float*)d_in[8];
  const float* bd1 = (const float*)d_in[9];  // cancels in BN algebra; unused
  const float* gm  = (const float*)d_in[10];
  const float* bt  = (const float*)d_in[11];
  const float* Wd2 = (const float*)d_in[12];
  const float* bd2 = (const float*)d_in[13];
  (void)bd1;

  const int N = in_sizes[0] / D;   // 100000
  const int E = in_sizes[1] / 2;   // 1600000

  float* h_out   = (float*)d_out;
  float* z_out   = h_out + (size_t)N * D;
  float* rec_out = z_out + (size_t)N * D;
  float* tgt_out = rec_out + (size_t)N * D;

  const size_t ws_need = ((size_t)3 * N + E + 4096) * 4
                       + (size_t)3 * N * D * 2 + 360448
                       + ((size_t)N + 128) * DDEC * 2 + 2048;
  const bool usews = ws_size >= ws_need;

  int *deg, *fillc, *bsum, *flag, *rowptr, *colidx;
  float *sums, *sumsq, *scale, *shift;
  ushort *xb, *hb, *aggrb, *wb;

  if (usews) {
    deg    = (int*)d_ws;                 // N
    fillc  = deg + N;                    // N
    sums   = (float*)(fillc + N);        // 512
    sumsq  = sums + 512;                 // 512   <- zero region: 2N+1024 ints
    scale  = sumsq + 512;
    shift  = scale + 512;
    bsum   = (int*)(shift + 512);        // 256
    flag   = bsum + 256;                 // 1 (+15 pad)
    rowptr = flag + 16;                  // N+1 (+pad)
    colidx = rowptr + (N + 16);          // E
    xb     = (ushort*)(((uintptr_t)(colidx + E) + 255) & ~(uintptr_t)255);
    hb     = xb + (size_t)N * D;
    aggrb  = hb + (size_t)N * D;
    wb     = aggrb + (size_t)N * D;      // 180224 (+ slack after for OOB-row reads)
  } else {
    sums   = (float*)d_ws;
    sumsq  = sums + DDEC;
    scale  = sumsq + DDEC;
    shift  = scale + DDEC;
    flag   = (int*)(shift + DDEC);
    bsum   = flag + 1;
    colidx = (int*)tgt_out;
    deg    = colidx + E;
    fillc  = deg + N;
    rowptr = fillc + N;
    xb     = (ushort*)(tgt_out + 2000000);
    wb     = (ushort*)(tgt_out + 8500000);
    aggrb  = (ushort*)z_out;
    hb     = aggrb + (size_t)N * D;
  }
  ushort* Wlb  = wb;
  ushort* Wrb  = wb + 16384;
  ushort* Wpb  = wb + 32768;
  ushort* Wd1b = wb + 49152;
  ushort* Wd2b = wb + 114688;

  if (usews) {
    hipMemsetAsync(deg, 0, (size_t)(2 * N + 1024) * sizeof(int), stream);
  } else {
    hipMemsetAsync(deg, 0, (size_t)2 * N * sizeof(int), stream);
    hipMemsetAsync(sums, 0, (size_t)2 * DDEC * sizeof(float), stream);
  }

  detect_i64<<<1, 64, 0, stream>>>(ei, flag);

  int n8 = N * (D / 8);
  int xblocks = (n8 + 255) / 256;
  int eb = (E + 255) / 256;
  prep_count_kernel<<<xblocks + 704 + eb, 256, 0, stream>>>(
      x, Wl, Wr, Wp, Wd1, Wd2, ei, xb, wb,
      usews ? tgt_out : nullptr, deg, flag, n8, xblocks, E);

  int NB = (N + 1023) / 1024;
  scan_reduce<<<NB, 256, 0, stream>>>(deg, bsum, N);
  scan_bsum<<<1, 256, 0, stream>>>(bsum, rowptr, NB, N, E);
  scan_final<<<NB, 256, 0, stream>>>(deg, bsum, rowptr, N);

  fill_csr<<<eb, 256, 0, stream>>>(ei, rowptr, fillc, colidx, flag, E);

  long long ag_threads = (long long)N * 64;
  aggregate_kernel<<<(int)((ag_threads + 255) / 256), 256, 0, stream>>>(
      rowptr, colidx, xb, aggrb, N);

  int rb = (N + 127) / 128;
  if (usews) {
    gemm_hz_dstat<<<rb, 256, 0, stream>>>(aggrb, xb, Wlb, Wrb, Wpb, Wd1b,
                                          bl, bp, ap, h_out, hb, z_out,
                                          sums, sumsq, N);
    finalize_kernel<<<2, 256, 0, stream>>>(sums, sumsq, gm, bt, scale, shift, N);
    rec_v4<<<rb, 256, 0, stream>>>(hb, Wd1b, Wd2b, scale, shift, bd2, rec_out, N);
  } else {
    gemm_h_mfma<<<rb, 256, 0, stream>>>(aggrb, xb, Wlb, Wrb, bl, h_out, hb, N);
    dstat_mfma<<<rb, 256, 0, stream>>>(hb, Wd1b, sums, sumsq, N);
    finalize_kernel<<<2, 256, 0, stream>>>(sums, sumsq, gm, bt, scale, shift, N);
    rec_mfma_fb<<<rb, 256, 0, stream>>>(hb, Wd1b, Wd2b, scale, shift, bd2, rec_out, N);
    gemm_z_staged<<<rb, 256, 0, stream>>>(h_out, Wpb, bp, ap, z_out, N);
    hipMemcpyAsync(tgt_out, x, (size_t)N * D * sizeof(float), hipMemcpyDeviceToDevice, stream);
  }
}

// Round 15
// 449.314 us; speedup vs baseline: 1.0006x; 1.0006x over previous
//
#include <hip/hip_runtime.h>
#include <cstdint>
#include <cstddef>

#define D 128
#define DDEC 512

typedef __attribute__((ext_vector_type(8))) short short8;
typedef __attribute__((ext_vector_type(4))) float f32x4;

__device__ __forceinline__ ushort f2bf(float f) {
  uint32_t u = __float_as_uint(f);
  u = u + 0x7FFF + ((u >> 16) & 1);   // round-to-nearest-even
  return (ushort)(u >> 16);
}
__device__ __forceinline__ float bf2f(ushort u) {
  return __uint_as_float(((uint32_t)u) << 16);
}

// ---------------------------------------------------------------- detect int64 layout (+zero counter)
__global__ void detect_i64(const int* __restrict__ ei, int* __restrict__ flag,
                           int* __restrict__ counter) {
  if (threadIdx.x == 0 && blockIdx.x == 0) {
    int allz = 1;
    for (int k = 0; k < 64; ++k)
      if (ei[2 * k + 1] != 0) { allz = 0; break; }
    *flag = allz ? 2 : 1;  // 2 => int64 storage read as int32 pairs
    *counter = 0;
  }
}

// ---------------------------------------------------------------- prep: xcvt (+tgt) + wcvt + count_deg
__global__ __launch_bounds__(256) void prep_count_kernel(
    const float* __restrict__ x, const float* __restrict__ Wl,
    const float* __restrict__ Wr, const float* __restrict__ Wp,
    const float* __restrict__ Wd1, const float* __restrict__ Wd2,
    const int* __restrict__ ei,
    ushort* __restrict__ xb, ushort* __restrict__ wb,
    float* __restrict__ tgt,   // may be null
    int* __restrict__ deg, const int* __restrict__ flag,
    int n8, int xblocks, int E)
{
  int b = blockIdx.x;
  if (b < xblocks) {
    int i = b * 256 + threadIdx.x;
    if (i >= n8) return;
    const float* s = x + (size_t)i * 8;
    float4 f0 = *(const float4*)s;
    float4 f1 = *(const float4*)(s + 4);
    short8 v;
    v[0] = (short)f2bf(f0.x); v[1] = (short)f2bf(f0.y);
    v[2] = (short)f2bf(f0.z); v[3] = (short)f2bf(f0.w);
    v[4] = (short)f2bf(f1.x); v[5] = (short)f2bf(f1.y);
    v[6] = (short)f2bf(f1.z); v[7] = (short)f2bf(f1.w);
    *(short8*)&xb[(size_t)i * 8] = v;
    if (tgt) {
      *(float4*)&tgt[(size_t)i * 8] = f0;
      *(float4*)&tgt[(size_t)i * 8 + 4] = f1;
    }
  } else if (b < xblocks + 704) {
    int i = (b - xblocks) * 256 + threadIdx.x;
    if (i >= 180224) return;
    float v;
    if (i < 16384) v = Wl[i];
    else if (i < 32768) v = Wr[i - 16384];
    else if (i < 49152) v = Wp[i - 32768];
    else if (i < 114688) v = Wd1[i - 49152];
    else v = Wd2[i - 114688];
    wb[i] = f2bf(v);
  } else {
    int e = (b - xblocks - 704) * 256 + threadIdx.x;
    if (e >= E) return;
    int s = *flag;
    int dst = ei[((long long)E + e) * s];
    atomicAdd(&deg[dst], 1);
  }
}

// ---------------------------------------------------------------- offsets: disjoint CSR ranges via
// wave-aggregated atomic (ranges need not be ordered; aggregate reads deg[] for length)
__global__ __launch_bounds__(256) void offsets_kernel(
    const int* __restrict__ deg, int* __restrict__ rowptr,
    int* __restrict__ counter, int N)
{
  int i = blockIdx.x * 256 + threadIdx.x;
  int lane = threadIdx.x & 63;
  int d = (i < N) ? deg[i] : 0;
  int incl = d;
#pragma unroll
  for (int off = 1; off < 64; off <<= 1) {
    int v = __shfl_up(incl, off);
    if (lane >= off) incl += v;
  }
  int total = __shfl(incl, 63);
  int base = 0;
  if (lane == 0 && total > 0) base = atomicAdd(counter, total);
  base = __shfl(base, 0);
  if (i < N) rowptr[i] = base + incl - d;
}

__global__ __launch_bounds__(256) void fill_csr(
    const int* __restrict__ ei, const int* __restrict__ rowptr,
    int* __restrict__ fillc, int* __restrict__ colidx,
    const int* __restrict__ flag, int E)
{
  int e = blockIdx.x * 256 + threadIdx.x;
  if (e >= E) return;
  int s = *flag;
  int src = ei[(long long)e * s];
  int dst = ei[((long long)E + e) * s];
  int pos = rowptr[dst] + atomicAdd(&fillc[dst], 1);
  colidx[pos] = src;
}

// ---------------------------------------------------------------- gather-mean (bf16)
__global__ __launch_bounds__(256) void aggregate_kernel(
    const int* __restrict__ rowptr, const int* __restrict__ deg,
    const int* __restrict__ colidx,
    const ushort* __restrict__ xb, ushort* __restrict__ aggrb, int N)
{
  int wave = (blockIdx.x * 256 + threadIdx.x) >> 6;
  int lane = threadIdx.x & 63;
  if (wave >= N) return;
  int s = rowptr[wave];
  int degn = deg[wave];
  int epos = s + degn;
  float ax = 0.f, ay = 0.f;
  int e = s;
  for (; e + 3 < epos; e += 4) {
    int s0 = colidx[e], s1 = colidx[e + 1], s2 = colidx[e + 2], s3 = colidx[e + 3];
    uint u0 = *(const uint*)&xb[(size_t)s0 * D + lane * 2];
    uint u1 = *(const uint*)&xb[(size_t)s1 * D + lane * 2];
    uint u2 = *(const uint*)&xb[(size_t)s2 * D + lane * 2];
    uint u3 = *(const uint*)&xb[(size_t)s3 * D + lane * 2];
    ax += __uint_as_float(u0 << 16) + __uint_as_float(u1 << 16)
        + __uint_as_float(u2 << 16) + __uint_as_float(u3 << 16);
    ay += __uint_as_float(u0 & 0xFFFF0000u) + __uint_as_float(u1 & 0xFFFF0000u)
        + __uint_as_float(u2 & 0xFFFF0000u) + __uint_as_float(u3 & 0xFFFF0000u);
  }
  for (; e < epos; ++e) {
    uint u0 = *(const uint*)&xb[(size_t)colidx[e] * D + lane * 2];
    ax += __uint_as_float(u0 << 16);
    ay += __uint_as_float(u0 & 0xFFFF0000u);
  }
  float inv = 1.0f / (float)(degn > 0 ? degn : 1);
  uint out = ((uint)f2bf(ax * inv)) | (((uint)f2bf(ay * inv)) << 16);
  *(uint*)&aggrb[(size_t)wave * D + lane * 2] = out;
}

// ---------------------------------------------------------------- MFMA helpers
__device__ __forceinline__ void mma_tile_g(const ushort* __restrict__ A, size_t ald,
                                           const ushort* __restrict__ B, size_t bld,
                                           f32x4 acc[4][4], int lane)
{
  const int r = lane & 15, g = lane >> 4;
#pragma unroll
  for (int ks = 0; ks < 4; ++ks) {
    short8 a[4], b[4];
#pragma unroll
    for (int m = 0; m < 4; ++m)
      a[m] = *(const short8*)&A[(size_t)(m * 16 + r) * ald + ks * 32 + g * 8];
#pragma unroll
    for (int n = 0; n < 4; ++n)
      b[n] = *(const short8*)&B[(size_t)(n * 16 + r) * bld + ks * 32 + g * 8];
#pragma unroll
    for (int m = 0; m < 4; ++m)
#pragma unroll
      for (int n = 0; n < 4; ++n)
        acc[m][n] = __builtin_amdgcn_mfma_f32_16x16x32_bf16(a[m], b[n], acc[m][n], 0, 0, 0);
  }
}

__device__ __forceinline__ void mma_tile_l(const ushort* aLds,
                                           const ushort* __restrict__ bGlb, size_t bld,
                                           f32x4 acc[4][4], int lane)
{
  const int r = lane & 15, g = lane >> 4;
#pragma unroll
  for (int ks = 0; ks < 4; ++ks) {
    short8 a[4], b[4];
#pragma unroll
    for (int m = 0; m < 4; ++m)
      a[m] = *(const short8*)&aLds[(m * 16 + r) * 136 + ks * 32 + g * 8];
#pragma unroll
    for (int n = 0; n < 4; ++n)
      b[n] = *(const short8*)&bGlb[(size_t)(n * 16 + r) * bld + ks * 32 + g * 8];
#pragma unroll
    for (int m = 0; m < 4; ++m)
#pragma unroll
      for (int n = 0; n < 4; ++n)
        acc[m][n] = __builtin_amdgcn_mfma_f32_16x16x32_bf16(a[m], b[n], acc[m][n], 0, 0, 0);
  }
}

// swapped-operand variant: out-col gets the (g*4+reg) mapping -> float4 stores
__device__ __forceinline__ void mma_tile_l_T(const ushort* aLds,
                                             const ushort* __restrict__ bGlb, size_t bld,
                                             f32x4 acc[4][4], int lane)
{
  const int r = lane & 15, g = lane >> 4;
#pragma unroll
  for (int ks = 0; ks < 4; ++ks) {
    short8 a[4], b[4];
#pragma unroll
    for (int m = 0; m < 4; ++m)
      a[m] = *(const short8*)&aLds[(m * 16 + r) * 136 + ks * 32 + g * 8];
#pragma unroll
    for (int n = 0; n < 4; ++n)
      b[n] = *(const short8*)&bGlb[(size_t)(n * 16 + r) * bld + ks * 32 + g * 8];
#pragma unroll
    for (int m = 0; m < 4; ++m)
#pragma unroll
      for (int n = 0; n < 4; ++n)
        acc[m][n] = __builtin_amdgcn_mfma_f32_16x16x32_bf16(b[n], a[m], acc[m][n], 0, 0, 0);
  }
}

// stage 128x128 f32 -> LDS bf16 [128][136] (fallback gemm_z only)
__device__ __forceinline__ void stage128(const float* __restrict__ src, int N,
                                         int row0, ushort* lds, int t)
{
#pragma unroll
  for (int p = 0; p < 8; ++p) {
    int r = (t >> 4) + p * 16;
    int c = (t & 15) * 8;
    short8 v = {};
    int row = row0 + r;
    if (row < N) {
      const float* s = src + (size_t)row * D + c;
      float4 f0 = *(const float4*)s;
      float4 f1 = *(const float4*)(s + 4);
      v[0] = (short)f2bf(f0.x); v[1] = (short)f2bf(f0.y);
      v[2] = (short)f2bf(f0.z); v[3] = (short)f2bf(f0.w);
      v[4] = (short)f2bf(f1.x); v[5] = (short)f2bf(f1.y);
      v[6] = (short)f2bf(f1.z); v[7] = (short)f2bf(f1.w);
    }
    *(short8*)&lds[r * 136 + c] = v;
  }
}

// ------------------------------------------------- FUSED: h-GEMM + z-GEMM + BN stats (r13)
__global__ __launch_bounds__(256, 3) void gemm_hz_dstat(
    const ushort* __restrict__ aggrb, const ushort* __restrict__ xb,
    const ushort* __restrict__ Wlb, const ushort* __restrict__ Wrb,
    const ushort* __restrict__ Wpb, const ushort* __restrict__ Wd1b,
    const float* __restrict__ bl, const float* __restrict__ bp,
    const float* __restrict__ ap,
    float* __restrict__ h, ushort* __restrict__ hb, float* __restrict__ z,
    float* __restrict__ sums, float* __restrict__ sumsq, int N)
{
  __shared__ ushort Hs[128 * 136];
  __shared__ float part1[2][8][132];
  __shared__ float part2[2][8][132];
  const int t = threadIdx.x;
  const int row0 = blockIdx.x * 128;
  const int lane = t & 63, w = t >> 6;
  const int wm = w >> 1, wn = w & 1;
  const int g = lane >> 4, cr = lane & 15;
  {
    f32x4 acc[4][4] = {};
    mma_tile_g(aggrb + (size_t)(row0 + wm * 64) * D, D, Wlb + (size_t)(wn * 64) * D, D, acc, lane);
    mma_tile_g(xb + (size_t)(row0 + wm * 64) * D, D, Wrb + (size_t)(wn * 64) * D, D, acc, lane);
#pragma unroll
    for (int n = 0; n < 4; ++n) {
      int col = wn * 64 + n * 16 + cr;
      float b = bl[col];
#pragma unroll
      for (int m = 0; m < 4; ++m)
#pragma unroll
        for (int rr = 0; rr < 4; ++rr) {
          int lrow = wm * 64 + m * 16 + g * 4 + rr;
          float v = acc[m][n][rr] + b;
          v = (v >= 0.f) ? v : 0.5f * v;
          Hs[lrow * 136 + col] = f2bf(v);
        }
    }
  }
  __syncthreads();
#pragma unroll
  for (int p = 0; p < 8; ++p) {
    int idx = t + p * 256;
    int r = idx >> 4, c = (idx & 15) * 8;
    int row = row0 + r;
    if (row < N) {
      short8 v = *(short8*)&Hs[r * 136 + c];
      *(short8*)&hb[(size_t)row * D + c] = v;
      float4 f0, f1;
      f0.x = bf2f((ushort)v[0]); f0.y = bf2f((ushort)v[1]);
      f0.z = bf2f((ushort)v[2]); f0.w = bf2f((ushort)v[3]);
      f1.x = bf2f((ushort)v[4]); f1.y = bf2f((ushort)v[5]);
      f1.z = bf2f((ushort)v[6]); f1.w = bf2f((ushort)v[7]);
      *(float4*)&h[(size_t)row * D + c] = f0;
      *(float4*)&h[(size_t)row * D + c + 4] = f1;
    }
  }
  {
    f32x4 zacc[4][4] = {};
    mma_tile_l_T(Hs + wm * 64 * 136, Wpb + (size_t)(wn * 64) * D, D, zacc, lane);
    const float alpha = ap[0];
#pragma unroll
    for (int m = 0; m < 4; ++m) {
      int row = row0 + wm * 64 + m * 16 + cr;
      if (row < N) {
#pragma unroll
        for (int n = 0; n < 4; ++n) {
          int col = wn * 64 + n * 16 + g * 4;
          float4 bv = *(const float4*)&bp[col];
          float4 o;
          float v0 = zacc[m][n][0] + bv.x; o.x = (v0 >= 0.f) ? v0 : alpha * v0;
          float v1 = zacc[m][n][1] + bv.y; o.y = (v1 >= 0.f) ? v1 : alpha * v1;
          float v2 = zacc[m][n][2] + bv.z; o.z = (v2 >= 0.f) ? v2 : alpha * v2;
          float v3 = zacc[m][n][3] + bv.w; o.w = (v3 >= 0.f) ? v3 : alpha * v3;
          *(float4*)&z[(size_t)row * D + col] = o;
        }
      }
    }
  }
  for (int cc = 0; cc < 4; ++cc) {
    int c0 = cc * 128;
    int pb = cc & 1;
    f32x4 dacc[4][4] = {};
    mma_tile_l(Hs + wm * 64 * 136, Wd1b + (size_t)(c0 + wn * 64) * D, D, dacc, lane);
#pragma unroll
    for (int n = 0; n < 4; ++n) {
      float s1 = 0.f, s2 = 0.f;
#pragma unroll
      for (int m = 0; m < 4; ++m)
#pragma unroll
        for (int rr = 0; rr < 4; ++rr) {
          int row = row0 + wm * 64 + m * 16 + g * 4 + rr;
          if (row < N) {
            float v = dacc[m][n][rr];
            s1 += v; s2 += v * v;
          }
        }
      part1[pb][wm * 4 + g][wn * 64 + n * 16 + cr] = s1;
      part2[pb][wm * 4 + g][wn * 64 + n * 16 + cr] = s2;
    }
    __syncthreads();
    if (t < 128) {
      float s = 0;
#pragma unroll
      for (int k = 0; k < 8; ++k) s += part1[pb][k][t];
      atomicAdd(&sums[c0 + t], s);
    } else {
      int c = t - 128;
      float s = 0;
#pragma unroll
      for (int k = 0; k < 8; ++k) s += part2[pb][k][c];
      atomicAdd(&sumsq[c0 + c], s);
    }
  }
}

__global__ void finalize_kernel(
    const float* __restrict__ sums, const float* __restrict__ sumsq,
    const float* __restrict__ gamma, const float* __restrict__ beta,
    float* __restrict__ scale, float* __restrict__ shift, int N)
{
  int c = blockIdx.x * blockDim.x + threadIdx.x;
  if (c < DDEC) {
    float inv_n = 1.0f / (float)N;
    float mu = sums[c] * inv_n;
    float var = sumsq[c] * inv_n - mu * mu;
    float sc = gamma[c] * rsqrtf(var + 1e-5f);
    scale[c] = sc;
    shift[c] = beta[c] - mu * sc;
  }
}

// ------------------------------------------------- rec (r13 champion)
__global__ __launch_bounds__(256, 2) void rec_mfma(
    const ushort* __restrict__ hb, const ushort* __restrict__ Wd1b,
    const ushort* __restrict__ Wd2b,
    const float* __restrict__ scale, const float* __restrict__ shift,
    const float* __restrict__ bd2, float* __restrict__ rec, int N)
{
  __shared__ ushort Hs[128 * 136];
  __shared__ ushort Dn[128 * 136];
  const int t = threadIdx.x;
  const int row0 = blockIdx.x * 128;
#pragma unroll
  for (int p = 0; p < 8; ++p) {
    int idx = t + p * 256;
    int r = idx >> 4, c = (idx & 15) * 8;
    short8 v = *(const short8*)&hb[(size_t)(row0 + r) * D + c];
    *(short8*)&Hs[r * 136 + c] = v;
  }
  const int lane = t & 63, w = t >> 6;
  const int wm = w >> 1, wn = w & 1;
  const int g = lane >> 4, cr = lane & 15;
  f32x4 acc[4][4] = {};
  __syncthreads();
  for (int c0 = 0; c0 < DDEC; c0 += 128) {
    f32x4 dacc[4][4] = {};
    mma_tile_l(Hs + wm * 64 * 136, Wd1b + (size_t)(c0 + wn * 64) * D, D, dacc, lane);
    __syncthreads();
#pragma unroll
    for (int n = 0; n < 4; ++n) {
      int lc = wn * 64 + n * 16 + cr;
      int c = c0 + lc;
      float sc = scale[c], sh = shift[c];
#pragma unroll
      for (int m = 0; m < 4; ++m)
#pragma unroll
        for (int rr = 0; rr < 4; ++rr) {
          float v = dacc[m][n][rr] * sc + sh;
          v = (v >= 0.f) ? v : 0.01f * v;
          Dn[(wm * 64 + m * 16 + g * 4 + rr) * 136 + lc] = f2bf(v);
        }
    }
    __syncthreads();
    mma_tile_l_T(Dn + wm * 64 * 136, Wd2b + (size_t)(wn * 64) * DDEC + c0, DDEC, acc, lane);
  }
#pragma unroll
  for (int m = 0; m < 4; ++m) {
    int row = row0 + wm * 64 + m * 16 + cr;
    if (row < N) {
#pragma unroll
      for (int n = 0; n < 4; ++n) {
        int col = wn * 64 + n * 16 + g * 4;
        float4 bv = *(const float4*)&bd2[col];
        float4 o;
        o.x = acc[m][n][0] + bv.x;
        o.y = acc[m][n][1] + bv.y;
        o.z = acc[m][n][2] + bv.z;
        o.w = acc[m][n][3] + bv.w;
        *(float4*)&rec[(size_t)row * D + col] = o;
      }
    }
  }
}

// ------------------------------------------------- fallback kernels (non-ws path)
__global__ __launch_bounds__(256, 3) void gemm_h_mfma(
    const ushort* __restrict__ aggrb, const ushort* __restrict__ xb,
    const ushort* __restrict__ Wlb, const ushort* __restrict__ Wrb,
    const float* __restrict__ bl, float* __restrict__ h,
    ushort* __restrict__ hb, int N)
{
  const int t = threadIdx.x;
  const int row0 = blockIdx.x * 128;
  const int lane = t & 63, w = t >> 6;
  const int wm = w >> 1, wn = w & 1;
  f32x4 acc[4][4] = {};
  mma_tile_g(aggrb + (size_t)(row0 + wm * 64) * D, D, Wlb + (size_t)(wn * 64) * D, D, acc, lane);
  mma_tile_g(xb + (size_t)(row0 + wm * 64) * D, D, Wrb + (size_t)(wn * 64) * D, D, acc, lane);
  const int g = lane >> 4, cr = lane & 15;
#pragma unroll
  for (int n = 0; n < 4; ++n) {
    int col = wn * 64 + n * 16 + cr;
    float b = bl[col];
#pragma unroll
    for (int m = 0; m < 4; ++m)
#pragma unroll
      for (int rr = 0; rr < 4; ++rr) {
        int row = row0 + wm * 64 + m * 16 + g * 4 + rr;
        if (row < N) {
          float v = acc[m][n][rr] + b;
          v = (v >= 0.f) ? v : 0.5f * v;
          h[(size_t)row * D + col] = v;
          hb[(size_t)row * D + col] = f2bf(v);
        }
      }
  }
}

__global__ __launch_bounds__(256, 4) void dstat_mfma(
    const ushort* __restrict__ hb, const ushort* __restrict__ Wd1b,
    float* __restrict__ sums, float* __restrict__ sumsq, int N)
{
  __shared__ float part1[8][132];
  __shared__ float part2[8][132];
  const int t = threadIdx.x;
  const int row0 = blockIdx.x * 128;
  const int lane = t & 63, w = t >> 6;
  const int wm = w >> 1, wn = w & 1;
  const int g = lane >> 4, cr = lane & 15;
  for (int c0 = 0; c0 < DDEC; c0 += 128) {
    f32x4 dacc[4][4] = {};
    mma_tile_g(hb + (size_t)(row0 + wm * 64) * D, D,
               Wd1b + (size_t)(c0 + wn * 64) * D, D, dacc, lane);
#pragma unroll
    for (int n = 0; n < 4; ++n) {
      float s1 = 0.f, s2 = 0.f;
#pragma unroll
      for (int m = 0; m < 4; ++m)
#pragma unroll
        for (int rr = 0; rr < 4; ++rr) {
          int row = row0 + wm * 64 + m * 16 + g * 4 + rr;
          if (row < N) {
            float v = dacc[m][n][rr];
            s1 += v; s2 += v * v;
          }
        }
      part1[wm * 4 + g][wn * 64 + n * 16 + cr] = s1;
      part2[wm * 4 + g][wn * 64 + n * 16 + cr] = s2;
    }
    __syncthreads();
    if (t < 128) {
      float s = 0;
#pragma unroll
      for (int k = 0; k < 8; ++k) s += part1[k][t];
      atomicAdd(&sums[c0 + t], s);
    } else {
      int c = t - 128;
      float s = 0;
#pragma unroll
      for (int k = 0; k < 8; ++k) s += part2[k][c];
      atomicAdd(&sumsq[c0 + c], s);
    }
    __syncthreads();
  }
}

__global__ __launch_bounds__(256, 2) void rec_mfma_fb(
    const ushort* __restrict__ hb, const ushort* __restrict__ Wd1b,
    const ushort* __restrict__ Wd2b,
    const float* __restrict__ scale, const float* __restrict__ shift,
    const float* __restrict__ bd2, float* __restrict__ rec, int N)
{
  __shared__ ushort Hs[128 * 136];
  __shared__ ushort Dn[128 * 136];
  const int t = threadIdx.x;
  const int row0 = blockIdx.x * 128;
#pragma unroll
  for (int p = 0; p < 8; ++p) {
    int idx = t + p * 256;
    int r = idx >> 4, c = (idx & 15) * 8;
    short8 v = *(const short8*)&hb[(size_t)(row0 + r) * D + c];
    *(short8*)&Hs[r * 136 + c] = v;
  }
  const int lane = t & 63, w = t >> 6;
  const int wm = w >> 1, wn = w & 1;
  const int g = lane >> 4, cr = lane & 15;
  f32x4 acc[4][4] = {};
  __syncthreads();
  for (int c0 = 0; c0 < DDEC; c0 += 128) {
    f32x4 dacc[4][4] = {};
    mma_tile_l(Hs + wm * 64 * 136, Wd1b + (size_t)(c0 + wn * 64) * D, D, dacc, lane);
    __syncthreads();
#pragma unroll
    for (int n = 0; n < 4; ++n) {
      int lc = wn * 64 + n * 16 + cr;
      int c = c0 + lc;
      float sc = scale[c], sh = shift[c];
#pragma unroll
      for (int m = 0; m < 4; ++m)
#pragma unroll
        for (int rr = 0; rr < 4; ++rr) {
          float v = dacc[m][n][rr] * sc + sh;
          v = (v >= 0.f) ? v : 0.01f * v;
          Dn[(wm * 64 + m * 16 + g * 4 + rr) * 136 + lc] = f2bf(v);
        }
    }
    __syncthreads();
    mma_tile_l(Dn + wm * 64 * 136, Wd2b + (size_t)(wn * 64) * DDEC + c0, DDEC, acc, lane);
  }
#pragma unroll
  for (int n = 0; n < 4; ++n) {
    int col = wn * 64 + n * 16 + cr;
    float b = bd2[col];
#pragma unroll
    for (int m = 0; m < 4; ++m)
#pragma unroll
      for (int rr = 0; rr < 4; ++rr) {
        int row = row0 + wm * 64 + m * 16 + g * 4 + rr;
        if (row < N) rec[(size_t)row * D + col] = acc[m][n][rr] + b;
      }
  }
}

__global__ __launch_bounds__(256, 2) void gemm_z_staged(
    const float* __restrict__ h, const ushort* __restrict__ Wpb,
    const float* __restrict__ bp, const float* __restrict__ ap,
    float* __restrict__ z, int N)
{
  __shared__ ushort As[128 * 136];
  const int t = threadIdx.x;
  const int row0 = blockIdx.x * 128;
  stage128(h, N, row0, As, t);
  __syncthreads();
  const int lane = t & 63, w = t >> 6;
  const int wm = w >> 1, wn = w & 1;
  f32x4 acc[4][4] = {};
  mma_tile_l(As + wm * 64 * 136, Wpb + (size_t)(wn * 64) * D, D, acc, lane);
  const float alpha = ap[0];
  const int g = lane >> 4, cr = lane & 15;
#pragma unroll
  for (int n = 0; n < 4; ++n) {
    int col = wn * 64 + n * 16 + cr;
    float b = bp[col];
#pragma unroll
    for (int m = 0; m < 4; ++m)
#pragma unroll
      for (int rr = 0; rr < 4; ++rr) {
        int row = row0 + wm * 64 + m * 16 + g * 4 + rr;
        if (row < N) {
          float v = acc[m][n][rr] + b;
          z[(size_t)row * D + col] = (v >= 0.f) ? v : alpha * v;
        }
      }
  }
}

// ---------------------------------------------------------------- launch
extern "C" void kernel_launch(void* const* d_in, const int* in_sizes, int n_in,
                              void* d_out, int out_size, void* d_ws, size_t ws_size,
                              hipStream_t stream)
{
  const float* x   = (const float*)d_in[0];
  const int*   ei  = (const int*)d_in[1];
  const float* Wl  = (const float*)d_in[2];
  const float* bl  = (const float*)d_in[3];
  const float* Wr  = (const float*)d_in[4];
  const float* Wp  = (const float*)d_in[5];
  const float* bp  = (const float*)d_in[6];
  const float* ap  = (const float*)d_in[7];
  const float* Wd1 = (const float*)d_in[8];
  const float* bd1 = (const float*)d_in[9];  // cancels in BN algebra; unused
  const float* gm  = (const float*)d_in[10];
  const float* bt  = (const float*)d_in[11];
  const float* Wd2 = (const float*)d_in[12];
  const float* bd2 = (const float*)d_in[13];
  (void)bd1;

  const int N = in_sizes[0] / D;   // 100000
  const int E = in_sizes[1] / 2;   // 1600000

  float* h_out   = (float*)d_out;
  float* z_out   = h_out + (size_t)N * D;
  float* rec_out = z_out + (size_t)N * D;
  float* tgt_out = rec_out + (size_t)N * D;

  const size_t ws_need = ((size_t)3 * N + E + 4096) * 4
                       + (size_t)3 * N * D * 2 + 360448
                       + ((size_t)N + 128) * DDEC * 2 + 2048;
  const bool usews = ws_size >= ws_need;

  int *deg, *fillc, *bsum, *flag, *rowptr, *colidx;
  float *sums, *sumsq, *scale, *shift;
  ushort *xb, *hb, *aggrb, *wb;

  if (usews) {
    deg    = (int*)d_ws;                 // N
    fillc  = deg + N;                    // N
    sums   = (float*)(fillc + N);        // 512
    sumsq  = sums + 512;                 // 512   <- zero region: 2N+1024 ints
    scale  = sumsq + 512;
    shift  = scale + 512;
    bsum   = (int*)(shift + 512);        // 256 (bsum[0] = counter)
    flag   = bsum + 256;                 // 1 (+15 pad)
    rowptr = flag + 16;                  // N+1 (+pad)
    colidx = rowptr + (N + 16);          // E
    xb     = (ushort*)(((uintptr_t)(colidx + E) + 255) & ~(uintptr_t)255);
    hb     = xb + (size_t)N * D;
    aggrb  = hb + (size_t)N * D;
    wb     = aggrb + (size_t)N * D;      // 180224 (+ slack after for OOB-row reads)
  } else {
    sums   = (float*)d_ws;
    sumsq  = sums + DDEC;
    scale  = sumsq + DDEC;
    shift  = scale + DDEC;
    flag   = (int*)(shift + DDEC);
    bsum   = flag + 1;
    colidx = (int*)tgt_out;
    deg    = colidx + E;
    fillc  = deg + N;
    rowptr = fillc + N;
    xb     = (ushort*)(tgt_out + 2000000);
    wb     = (ushort*)(tgt_out + 8500000);
    aggrb  = (ushort*)z_out;
    hb     = aggrb + (size_t)N * D;
  }
  ushort* Wlb  = wb;
  ushort* Wrb  = wb + 16384;
  ushort* Wpb  = wb + 32768;
  ushort* Wd1b = wb + 49152;
  ushort* Wd2b = wb + 114688;
  int* counter = bsum;

  if (usews) {
    hipMemsetAsync(deg, 0, (size_t)(2 * N + 1024) * sizeof(int), stream);
  } else {
    hipMemsetAsync(deg, 0, (size_t)2 * N * sizeof(int), stream);
    hipMemsetAsync(sums, 0, (size_t)2 * DDEC * sizeof(float), stream);
  }

  detect_i64<<<1, 64, 0, stream>>>(ei, flag, counter);

  int n8 = N * (D / 8);
  int xblocks = (n8 + 255) / 256;
  int eb = (E + 255) / 256;
  prep_count_kernel<<<xblocks + 704 + eb, 256, 0, stream>>>(
      x, Wl, Wr, Wp, Wd1, Wd2, ei, xb, wb,
      usews ? tgt_out : nullptr, deg, flag, n8, xblocks, E);

  offsets_kernel<<<(N + 255) / 256, 256, 0, stream>>>(deg, rowptr, counter, N);

  fill_csr<<<eb, 256, 0, stream>>>(ei, rowptr, fillc, colidx, flag, E);

  long long ag_threads = (long long)N * 64;
  aggregate_kernel<<<(int)((ag_threads + 255) / 256), 256, 0, stream>>>(
      rowptr, deg, colidx, xb, aggrb, N);

  int rb = (N + 127) / 128;
  if (usews) {
    gemm_hz_dstat<<<rb, 256, 0, stream>>>(aggrb, xb, Wlb, Wrb, Wpb, Wd1b,
                                          bl, bp, ap, h_out, hb, z_out,
                                          sums, sumsq, N);
    finalize_kernel<<<2, 256, 0, stream>>>(sums, sumsq, gm, bt, scale, shift, N);
    rec_mfma<<<rb, 256, 0, stream>>>(hb, Wd1b, Wd2b, scale, shift, bd2, rec_out, N);
  } else {
    gemm_h_mfma<<<rb, 256, 0, stream>>>(aggrb, xb, Wlb, Wrb, bl, h_out, hb, N);
    dstat_mfma<<<rb, 256, 0, stream>>>(hb, Wd1b, sums, sumsq, N);
    finalize_kernel<<<2, 256, 0, stream>>>(sums, sumsq, gm, bt, scale, shift, N);
    rec_mfma_fb<<<rb, 256, 0, stream>>>(hb, Wd1b, Wd2b, scale, shift, bd2, rec_out, N);
    gemm_z_staged<<<rb, 256, 0, stream>>>(h_out, Wpb, bp, ap, z_out, N);
    hipMemcpyAsync(tgt_out, x, (size_t)N * D * sizeof(float), hipMemcpyDeviceToDevice, stream);
  }
}

// Round 16
// 429.099 us; speedup vs baseline: 1.0477x; 1.0471x over previous
//
#include <hip/hip_runtime.h>
#include <cstdint>
#include <cstddef>

#define D 128
#define DDEC 512

typedef __attribute__((ext_vector_type(8))) short short8;
typedef __attribute__((ext_vector_type(4))) float f32x4;

__device__ __forceinline__ ushort f2bf(float f) {
  uint32_t u = __float_as_uint(f);
  u = u + 0x7FFF + ((u >> 16) & 1);   // round-to-nearest-even
  return (ushort)(u >> 16);
}
__device__ __forceinline__ float bf2f(ushort u) {
  return __uint_as_float(((uint32_t)u) << 16);
}

// ---------------------------------------------------------------- init: zero scratch + detect int64
// replaces hipMemsetAsync (whose graph fill-node showed ~116us/replay in rocprof)
__global__ __launch_bounds__(256) void init_kernel(
    const int* __restrict__ ei, int* __restrict__ flag,
    int4* __restrict__ zb, int nz4, int zblocks)
{
  int b = blockIdx.x;
  if (b < zblocks) {
    int i = b * 256 + threadIdx.x;
    if (i < nz4) zb[i] = make_int4(0, 0, 0, 0);
  } else if (threadIdx.x == 0) {
    int allz = 1;
    for (int k = 0; k < 64; ++k)
      if (ei[2 * k + 1] != 0) { allz = 0; break; }
    *flag = allz ? 2 : 1;  // 2 => int64 storage read as int32 pairs
  }
}

// ---------------------------------------------------------------- prep: xcvt (+tgt) + wcvt + count_deg
__global__ __launch_bounds__(256) void prep_count_kernel(
    const float* __restrict__ x, const float* __restrict__ Wl,
    const float* __restrict__ Wr, const float* __restrict__ Wp,
    const float* __restrict__ Wd1, const float* __restrict__ Wd2,
    const int* __restrict__ ei,
    ushort* __restrict__ xb, ushort* __restrict__ wb,
    float* __restrict__ tgt,   // may be null
    int* __restrict__ deg, const int* __restrict__ flag,
    int n8, int xblocks, int E)
{
  int b = blockIdx.x;
  if (b < xblocks) {
    int i = b * 256 + threadIdx.x;
    if (i >= n8) return;
    const float* s = x + (size_t)i * 8;
    float4 f0 = *(const float4*)s;
    float4 f1 = *(const float4*)(s + 4);
    short8 v;
    v[0] = (short)f2bf(f0.x); v[1] = (short)f2bf(f0.y);
    v[2] = (short)f2bf(f0.z); v[3] = (short)f2bf(f0.w);
    v[4] = (short)f2bf(f1.x); v[5] = (short)f2bf(f1.y);
    v[6] = (short)f2bf(f1.z); v[7] = (short)f2bf(f1.w);
    *(short8*)&xb[(size_t)i * 8] = v;
    if (tgt) {
      *(float4*)&tgt[(size_t)i * 8] = f0;
      *(float4*)&tgt[(size_t)i * 8 + 4] = f1;
    }
  } else if (b < xblocks + 704) {
    int i = (b - xblocks) * 256 + threadIdx.x;
    if (i >= 180224) return;
    float v;
    if (i < 16384) v = Wl[i];
    else if (i < 32768) v = Wr[i - 16384];
    else if (i < 49152) v = Wp[i - 32768];
    else if (i < 114688) v = Wd1[i - 49152];
    else v = Wd2[i - 114688];
    wb[i] = f2bf(v);
  } else {
    int e = (b - xblocks - 704) * 256 + threadIdx.x;
    if (e >= E) return;
    int s = *flag;
    int dst = ei[((long long)E + e) * s];
    atomicAdd(&deg[dst], 1);
  }
}

// ---------------------------------------------------------------- CSR scan + fill (r13 3-scan)
__global__ __launch_bounds__(256) void scan_reduce(
    const int* __restrict__ deg, int* __restrict__ bsum, int N)
{
  __shared__ int red[256];
  int base = blockIdx.x * 1024 + threadIdx.x * 4;
  int s = 0;
#pragma unroll
  for (int k = 0; k < 4; ++k) { int i = base + k; if (i < N) s += deg[i]; }
  red[threadIdx.x] = s;
  __syncthreads();
  for (int off = 128; off > 0; off >>= 1) {
    if (threadIdx.x < off) red[threadIdx.x] += red[threadIdx.x + off];
    __syncthreads();
  }
  if (threadIdx.x == 0) bsum[blockIdx.x] = red[0];
}

__global__ void scan_bsum(int* __restrict__ bsum, int* __restrict__ rowptr,
                          int NB, int N, int E)
{
  __shared__ int tmp[256];
  int t = threadIdx.x;
  int v = (t < NB) ? bsum[t] : 0;
  tmp[t] = v;
  __syncthreads();
  for (int off = 1; off < 256; off <<= 1) {
    int add = (t >= off) ? tmp[t - off] : 0;
    __syncthreads();
    tmp[t] += add;
    __syncthreads();
  }
  if (t < NB) bsum[t] = tmp[t] - v;  // exclusive
  if (t == 0) rowptr[N] = E;
}

__global__ __launch_bounds__(256) void scan_final(
    const int* __restrict__ deg, const int* __restrict__ bsum,
    int* __restrict__ rowptr, int N)
{
  __shared__ int tsum[256];
  int base = blockIdx.x * 1024 + threadIdx.x * 4;
  int loc[4]; int s = 0;
#pragma unroll
  for (int k = 0; k < 4; ++k) { int i = base + k; loc[k] = (i < N) ? deg[i] : 0; s += loc[k]; }
  tsum[threadIdx.x] = s;
  __syncthreads();
  for (int off = 1; off < 256; off <<= 1) {
    int add = (threadIdx.x >= off) ? tsum[threadIdx.x - off] : 0;
    __syncthreads();
    tsum[threadIdx.x] += add;
    __syncthreads();
  }
  int excl = tsum[threadIdx.x] - s + bsum[blockIdx.x];
#pragma unroll
  for (int k = 0; k < 4; ++k) {
    int i = base + k;
    if (i < N) { rowptr[i] = excl; excl += loc[k]; }
  }
}

__global__ __launch_bounds__(256) void fill_csr(
    const int* __restrict__ ei, const int* __restrict__ rowptr,
    int* __restrict__ fillc, int* __restrict__ colidx,
    const int* __restrict__ flag, int E)
{
  int e = blockIdx.x * 256 + threadIdx.x;
  if (e >= E) return;
  int s = *flag;
  int src = ei[(long long)e * s];
  int dst = ei[((long long)E + e) * s];
  int pos = rowptr[dst] + atomicAdd(&fillc[dst], 1);
  colidx[pos] = src;
}

// ---------------------------------------------------------------- gather-mean (bf16)
__global__ __launch_bounds__(256) void aggregate_kernel(
    const int* __restrict__ rowptr, const int* __restrict__ colidx,
    const ushort* __restrict__ xb, ushort* __restrict__ aggrb, int N)
{
  int wave = (blockIdx.x * 256 + threadIdx.x) >> 6;
  int lane = threadIdx.x & 63;
  if (wave >= N) return;
  int s = rowptr[wave], epos = rowptr[wave + 1];
  float ax = 0.f, ay = 0.f;
  int e = s;
  for (; e + 3 < epos; e += 4) {
    int s0 = colidx[e], s1 = colidx[e + 1], s2 = colidx[e + 2], s3 = colidx[e + 3];
    uint u0 = *(const uint*)&xb[(size_t)s0 * D + lane * 2];
    uint u1 = *(const uint*)&xb[(size_t)s1 * D + lane * 2];
    uint u2 = *(const uint*)&xb[(size_t)s2 * D + lane * 2];
    uint u3 = *(const uint*)&xb[(size_t)s3 * D + lane * 2];
    ax += __uint_as_float(u0 << 16) + __uint_as_float(u1 << 16)
        + __uint_as_float(u2 << 16) + __uint_as_float(u3 << 16);
    ay += __uint_as_float(u0 & 0xFFFF0000u) + __uint_as_float(u1 & 0xFFFF0000u)
        + __uint_as_float(u2 & 0xFFFF0000u) + __uint_as_float(u3 & 0xFFFF0000u);
  }
  for (; e < epos; ++e) {
    uint u0 = *(const uint*)&xb[(size_t)colidx[e] * D + lane * 2];
    ax += __uint_as_float(u0 << 16);
    ay += __uint_as_float(u0 & 0xFFFF0000u);
  }
  int degn = epos - s;
  float inv = 1.0f / (float)(degn > 0 ? degn : 1);
  uint out = ((uint)f2bf(ax * inv)) | (((uint)f2bf(ay * inv)) << 16);
  *(uint*)&aggrb[(size_t)wave * D + lane * 2] = out;
}

// ---------------------------------------------------------------- MFMA helpers
__device__ __forceinline__ void mma_tile_g(const ushort* __restrict__ A, size_t ald,
                                           const ushort* __restrict__ B, size_t bld,
                                           f32x4 acc[4][4], int lane)
{
  const int r = lane & 15, g = lane >> 4;
#pragma unroll
  for (int ks = 0; ks < 4; ++ks) {
    short8 a[4], b[4];
#pragma unroll
    for (int m = 0; m < 4; ++m)
      a[m] = *(const short8*)&A[(size_t)(m * 16 + r) * ald + ks * 32 + g * 8];
#pragma unroll
    for (int n = 0; n < 4; ++n)
      b[n] = *(const short8*)&B[(size_t)(n * 16 + r) * bld + ks * 32 + g * 8];
#pragma unroll
    for (int m = 0; m < 4; ++m)
#pragma unroll
      for (int n = 0; n < 4; ++n)
        acc[m][n] = __builtin_amdgcn_mfma_f32_16x16x32_bf16(a[m], b[n], acc[m][n], 0, 0, 0);
  }
}

__device__ __forceinline__ void mma_tile_l(const ushort* aLds,
                                           const ushort* __restrict__ bGlb, size_t bld,
                                           f32x4 acc[4][4], int lane)
{
  const int r = lane & 15, g = lane >> 4;
#pragma unroll
  for (int ks = 0; ks < 4; ++ks) {
    short8 a[4], b[4];
#pragma unroll
    for (int m = 0; m < 4; ++m)
      a[m] = *(const short8*)&aLds[(m * 16 + r) * 136 + ks * 32 + g * 8];
#pragma unroll
    for (int n = 0; n < 4; ++n)
      b[n] = *(const short8*)&bGlb[(size_t)(n * 16 + r) * bld + ks * 32 + g * 8];
#pragma unroll
    for (int m = 0; m < 4; ++m)
#pragma unroll
      for (int n = 0; n < 4; ++n)
        acc[m][n] = __builtin_amdgcn_mfma_f32_16x16x32_bf16(a[m], b[n], acc[m][n], 0, 0, 0);
  }
}

// swapped-operand variant: out-col gets the (g*4+reg) mapping -> float4 stores
__device__ __forceinline__ void mma_tile_l_T(const ushort* aLds,
                                             const ushort* __restrict__ bGlb, size_t bld,
                                             f32x4 acc[4][4], int lane)
{
  const int r = lane & 15, g = lane >> 4;
#pragma unroll
  for (int ks = 0; ks < 4; ++ks) {
    short8 a[4], b[4];
#pragma unroll
    for (int m = 0; m < 4; ++m)
      a[m] = *(const short8*)&aLds[(m * 16 + r) * 136 + ks * 32 + g * 8];
#pragma unroll
    for (int n = 0; n < 4; ++n)
      b[n] = *(const short8*)&bGlb[(size_t)(n * 16 + r) * bld + ks * 32 + g * 8];
#pragma unroll
    for (int m = 0; m < 4; ++m)
#pragma unroll
      for (int n = 0; n < 4; ++n)
        acc[m][n] = __builtin_amdgcn_mfma_f32_16x16x32_bf16(b[n], a[m], acc[m][n], 0, 0, 0);
  }
}

// stage 128x128 f32 -> LDS bf16 [128][136] (fallback gemm_z only)
__device__ __forceinline__ void stage128(const float* __restrict__ src, int N,
                                         int row0, ushort* lds, int t)
{
#pragma unroll
  for (int p = 0; p < 8; ++p) {
    int r = (t >> 4) + p * 16;
    int c = (t & 15) * 8;
    short8 v = {};
    int row = row0 + r;
    if (row < N) {
      const float* s = src + (size_t)row * D + c;
      float4 f0 = *(const float4*)s;
      float4 f1 = *(const float4*)(s + 4);
      v[0] = (short)f2bf(f0.x); v[1] = (short)f2bf(f0.y);
      v[2] = (short)f2bf(f0.z); v[3] = (short)f2bf(f0.w);
      v[4] = (short)f2bf(f1.x); v[5] = (short)f2bf(f1.y);
      v[6] = (short)f2bf(f1.z); v[7] = (short)f2bf(f1.w);
    }
    *(short8*)&lds[r * 136 + c] = v;
  }
}

// ------------------------------------------------- FUSED: h-GEMM + z-GEMM + BN stats (r13)
__global__ __launch_bounds__(256, 3) void gemm_hz_dstat(
    const ushort* __restrict__ aggrb, const ushort* __restrict__ xb,
    const ushort* __restrict__ Wlb, const ushort* __restrict__ Wrb,
    const ushort* __restrict__ Wpb, const ushort* __restrict__ Wd1b,
    const float* __restrict__ bl, const float* __restrict__ bp,
    const float* __restrict__ ap,
    float* __restrict__ h, ushort* __restrict__ hb, float* __restrict__ z,
    float* __restrict__ sums, float* __restrict__ sumsq, int N)
{
  __shared__ ushort Hs[128 * 136];
  __shared__ float part1[2][8][132];
  __shared__ float part2[2][8][132];
  const int t = threadIdx.x;
  const int row0 = blockIdx.x * 128;
  const int lane = t & 63, w = t >> 6;
  const int wm = w >> 1, wn = w & 1;
  const int g = lane >> 4, cr = lane & 15;
  {
    f32x4 acc[4][4] = {};
    mma_tile_g(aggrb + (size_t)(row0 + wm * 64) * D, D, Wlb + (size_t)(wn * 64) * D, D, acc, lane);
    mma_tile_g(xb + (size_t)(row0 + wm * 64) * D, D, Wrb + (size_t)(wn * 64) * D, D, acc, lane);
#pragma unroll
    for (int n = 0; n < 4; ++n) {
      int col = wn * 64 + n * 16 + cr;
      float b = bl[col];
#pragma unroll
      for (int m = 0; m < 4; ++m)
#pragma unroll
        for (int rr = 0; rr < 4; ++rr) {
          int lrow = wm * 64 + m * 16 + g * 4 + rr;
          float v = acc[m][n][rr] + b;
          v = (v >= 0.f) ? v : 0.5f * v;
          Hs[lrow * 136 + col] = f2bf(v);
        }
    }
  }
  __syncthreads();
#pragma unroll
  for (int p = 0; p < 8; ++p) {
    int idx = t + p * 256;
    int r = idx >> 4, c = (idx & 15) * 8;
    int row = row0 + r;
    if (row < N) {
      short8 v = *(short8*)&Hs[r * 136 + c];
      *(short8*)&hb[(size_t)row * D + c] = v;
      float4 f0, f1;
      f0.x = bf2f((ushort)v[0]); f0.y = bf2f((ushort)v[1]);
      f0.z = bf2f((ushort)v[2]); f0.w = bf2f((ushort)v[3]);
      f1.x = bf2f((ushort)v[4]); f1.y = bf2f((ushort)v[5]);
      f1.z = bf2f((ushort)v[6]); f1.w = bf2f((ushort)v[7]);
      *(float4*)&h[(size_t)row * D + c] = f0;
      *(float4*)&h[(size_t)row * D + c + 4] = f1;
    }
  }
  {
    f32x4 zacc[4][4] = {};
    mma_tile_l_T(Hs + wm * 64 * 136, Wpb + (size_t)(wn * 64) * D, D, zacc, lane);
    const float alpha = ap[0];
#pragma unroll
    for (int m = 0; m < 4; ++m) {
      int row = row0 + wm * 64 + m * 16 + cr;
      if (row < N) {
#pragma unroll
        for (int n = 0; n < 4; ++n) {
          int col = wn * 64 + n * 16 + g * 4;
          float4 bv = *(const float4*)&bp[col];
          float4 o;
          float v0 = zacc[m][n][0] + bv.x; o.x = (v0 >= 0.f) ? v0 : alpha * v0;
          float v1 = zacc[m][n][1] + bv.y; o.y = (v1 >= 0.f) ? v1 : alpha * v1;
          float v2 = zacc[m][n][2] + bv.z; o.z = (v2 >= 0.f) ? v2 : alpha * v2;
          float v3 = zacc[m][n][3] + bv.w; o.w = (v3 >= 0.f) ? v3 : alpha * v3;
          *(float4*)&z[(size_t)row * D + col] = o;
        }
      }
    }
  }
  for (int cc = 0; cc < 4; ++cc) {
    int c0 = cc * 128;
    int pb = cc & 1;
    f32x4 dacc[4][4] = {};
    mma_tile_l(Hs + wm * 64 * 136, Wd1b + (size_t)(c0 + wn * 64) * D, D, dacc, lane);
#pragma unroll
    for (int n = 0; n < 4; ++n) {
      float s1 = 0.f, s2 = 0.f;
#pragma unroll
      for (int m = 0; m < 4; ++m)
#pragma unroll
        for (int rr = 0; rr < 4; ++rr) {
          int row = row0 + wm * 64 + m * 16 + g * 4 + rr;
          if (row < N) {
            float v = dacc[m][n][rr];
            s1 += v; s2 += v * v;
          }
        }
      part1[pb][wm * 4 + g][wn * 64 + n * 16 + cr] = s1;
      part2[pb][wm * 4 + g][wn * 64 + n * 16 + cr] = s2;
    }
    __syncthreads();
    if (t < 128) {
      float s = 0;
#pragma unroll
      for (int k = 0; k < 8; ++k) s += part1[pb][k][t];
      atomicAdd(&sums[c0 + t], s);
    } else {
      int c = t - 128;
      float s = 0;
#pragma unroll
      for (int k = 0; k < 8; ++k) s += part2[pb][k][c];
      atomicAdd(&sumsq[c0 + c], s);
    }
  }
}

__global__ void finalize_kernel(
    const float* __restrict__ sums, const float* __restrict__ sumsq,
    const float* __restrict__ gamma, const float* __restrict__ beta,
    float* __restrict__ scale, float* __restrict__ shift, int N)
{
  int c = blockIdx.x * blockDim.x + threadIdx.x;
  if (c < DDEC) {
    float inv_n = 1.0f / (float)N;
    float mu = sums[c] * inv_n;
    float var = sumsq[c] * inv_n - mu * mu;
    float sc = gamma[c] * rsqrtf(var + 1e-5f);
    scale[c] = sc;
    shift[c] = beta[c] - mu * sc;
  }
}

// ------------------------------------------------- rec (r13 champion)
__global__ __launch_bounds__(256, 2) void rec_mfma(
    const ushort* __restrict__ hb, const ushort* __restrict__ Wd1b,
    const ushort* __restrict__ Wd2b,
    const float* __restrict__ scale, const float* __restrict__ shift,
    const float* __restrict__ bd2, float* __restrict__ rec, int N)
{
  __shared__ ushort Hs[128 * 136];
  __shared__ ushort Dn[128 * 136];
  const int t = threadIdx.x;
  const int row0 = blockIdx.x * 128;
#pragma unroll
  for (int p = 0; p < 8; ++p) {
    int idx = t + p * 256;
    int r = idx >> 4, c = (idx & 15) * 8;
    short8 v = *(const short8*)&hb[(size_t)(row0 + r) * D + c];
    *(short8*)&Hs[r * 136 + c] = v;
  }
  const int lane = t & 63, w = t >> 6;
  const int wm = w >> 1, wn = w & 1;
  const int g = lane >> 4, cr = lane & 15;
  f32x4 acc[4][4] = {};
  __syncthreads();
  for (int c0 = 0; c0 < DDEC; c0 += 128) {
    f32x4 dacc[4][4] = {};
    mma_tile_l(Hs + wm * 64 * 136, Wd1b + (size_t)(c0 + wn * 64) * D, D, dacc, lane);
    __syncthreads();
#pragma unroll
    for (int n = 0; n < 4; ++n) {
      int lc = wn * 64 + n * 16 + cr;
      int c = c0 + lc;
      float sc = scale[c], sh = shift[c];
#pragma unroll
      for (int m = 0; m < 4; ++m)
#pragma unroll
        for (int rr = 0; rr < 4; ++rr) {
          float v = dacc[m][n][rr] * sc + sh;
          v = (v >= 0.f) ? v : 0.01f * v;
          Dn[(wm * 64 + m * 16 + g * 4 + rr) * 136 + lc] = f2bf(v);
        }
    }
    __syncthreads();
    mma_tile_l_T(Dn + wm * 64 * 136, Wd2b + (size_t)(wn * 64) * DDEC + c0, DDEC, acc, lane);
  }
#pragma unroll
  for (int m = 0; m < 4; ++m) {
    int row = row0 + wm * 64 + m * 16 + cr;
    if (row < N) {
#pragma unroll
      for (int n = 0; n < 4; ++n) {
        int col = wn * 64 + n * 16 + g * 4;
        float4 bv = *(const float4*)&bd2[col];
        float4 o;
        o.x = acc[m][n][0] + bv.x;
        o.y = acc[m][n][1] + bv.y;
        o.z = acc[m][n][2] + bv.z;
        o.w = acc[m][n][3] + bv.w;
        *(float4*)&rec[(size_t)row * D + col] = o;
      }
    }
  }
}

// ------------------------------------------------- fallback kernels (non-ws path)
__global__ __launch_bounds__(256, 3) void gemm_h_mfma(
    const ushort* __restrict__ aggrb, const ushort* __restrict__ xb,
    const ushort* __restrict__ Wlb, const ushort* __restrict__ Wrb,
    const float* __restrict__ bl, float* __restrict__ h,
    ushort* __restrict__ hb, int N)
{
  const int t = threadIdx.x;
  const int row0 = blockIdx.x * 128;
  const int lane = t & 63, w = t >> 6;
  const int wm = w >> 1, wn = w & 1;
  f32x4 acc[4][4] = {};
  mma_tile_g(aggrb + (size_t)(row0 + wm * 64) * D, D, Wlb + (size_t)(wn * 64) * D, D, acc, lane);
  mma_tile_g(xb + (size_t)(row0 + wm * 64) * D, D, Wrb + (size_t)(wn * 64) * D, D, acc, lane);
  const int g = lane >> 4, cr = lane & 15;
#pragma unroll
  for (int n = 0; n < 4; ++n) {
    int col = wn * 64 + n * 16 + cr;
    float b = bl[col];
#pragma unroll
    for (int m = 0; m < 4; ++m)
#pragma unroll
      for (int rr = 0; rr < 4; ++rr) {
        int row = row0 + wm * 64 + m * 16 + g * 4 + rr;
        if (row < N) {
          float v = acc[m][n][rr] + b;
          v = (v >= 0.f) ? v : 0.5f * v;
          h[(size_t)row * D + col] = v;
          hb[(size_t)row * D + col] = f2bf(v);
        }
      }
  }
}

__global__ __launch_bounds__(256, 4) void dstat_mfma(
    const ushort* __restrict__ hb, const ushort* __restrict__ Wd1b,
    float* __restrict__ sums, float* __restrict__ sumsq, int N)
{
  __shared__ float part1[8][132];
  __shared__ float part2[8][132];
  const int t = threadIdx.x;
  const int row0 = blockIdx.x * 128;
  const int lane = t & 63, w = t >> 6;
  const int wm = w >> 1, wn = w & 1;
  const int g = lane >> 4, cr = lane & 15;
  for (int c0 = 0; c0 < DDEC; c0 += 128) {
    f32x4 dacc[4][4] = {};
    mma_tile_g(hb + (size_t)(row0 + wm * 64) * D, D,
               Wd1b + (size_t)(c0 + wn * 64) * D, D, dacc, lane);
#pragma unroll
    for (int n = 0; n < 4; ++n) {
      float s1 = 0.f, s2 = 0.f;
#pragma unroll
      for (int m = 0; m < 4; ++m)
#pragma unroll
        for (int rr = 0; rr < 4; ++rr) {
          int row = row0 + wm * 64 + m * 16 + g * 4 + rr;
          if (row < N) {
            float v = dacc[m][n][rr];
            s1 += v; s2 += v * v;
          }
        }
      part1[wm * 4 + g][wn * 64 + n * 16 + cr] = s1;
      part2[wm * 4 + g][wn * 64 + n * 16 + cr] = s2;
    }
    __syncthreads();
    if (t < 128) {
      float s = 0;
#pragma unroll
      for (int k = 0; k < 8; ++k) s += part1[k][t];
      atomicAdd(&sums[c0 + t], s);
    } else {
      int c = t - 128;
      float s = 0;
#pragma unroll
      for (int k = 0; k < 8; ++k) s += part2[k][c];
      atomicAdd(&sumsq[c0 + c], s);
    }
    __syncthreads();
  }
}

__global__ __launch_bounds__(256, 2) void rec_mfma_fb(
    const ushort* __restrict__ hb, const ushort* __restrict__ Wd1b,
    const ushort* __restrict__ Wd2b,
    const float* __restrict__ scale, const float* __restrict__ shift,
    const float* __restrict__ bd2, float* __restrict__ rec, int N)
{
  __shared__ ushort Hs[128 * 136];
  __shared__ ushort Dn[128 * 136];
  const int t = threadIdx.x;
  const int row0 = blockIdx.x * 128;
#pragma unroll
  for (int p = 0; p < 8; ++p) {
    int idx = t + p * 256;
    int r = idx >> 4, c = (idx & 15) * 8;
    short8 v = *(const short8*)&hb[(size_t)(row0 + r) * D + c];
    *(short8*)&Hs[r * 136 + c] = v;
  }
  const int lane = t & 63, w = t >> 6;
  const int wm = w >> 1, wn = w & 1;
  const int g = lane >> 4, cr = lane & 15;
  f32x4 acc[4][4] = {};
  __syncthreads();
  for (int c0 = 0; c0 < DDEC; c0 += 128) {
    f32x4 dacc[4][4] = {};
    mma_tile_l(Hs + wm * 64 * 136, Wd1b + (size_t)(c0 + wn * 64) * D, D, dacc, lane);
    __syncthreads();
#pragma unroll
    for (int n = 0; n < 4; ++n) {
      int lc = wn * 64 + n * 16 + cr;
      int c = c0 + lc;
      float sc = scale[c], sh = shift[c];
#pragma unroll
      for (int m = 0; m < 4; ++m)
#pragma unroll
        for (int rr = 0; rr < 4; ++rr) {
          float v = dacc[m][n][rr] * sc + sh;
          v = (v >= 0.f) ? v : 0.01f * v;
          Dn[(wm * 64 + m * 16 + g * 4 + rr) * 136 + lc] = f2bf(v);
        }
    }
    __syncthreads();
    mma_tile_l(Dn + wm * 64 * 136, Wd2b + (size_t)(wn * 64) * DDEC + c0, DDEC, acc, lane);
  }
#pragma unroll
  for (int n = 0; n < 4; ++n) {
    int col = wn * 64 + n * 16 + cr;
    float b = bd2[col];
#pragma unroll
    for (int m = 0; m < 4; ++m)
#pragma unroll
      for (int rr = 0; rr < 4; ++rr) {
        int row = row0 + wm * 64 + m * 16 + g * 4 + rr;
        if (row < N) rec[(size_t)row * D + col] = acc[m][n][rr] + b;
      }
  }
}

__global__ __launch_bounds__(256, 2) void gemm_z_staged(
    const float* __restrict__ h, const ushort* __restrict__ Wpb,
    const float* __restrict__ bp, const float* __restrict__ ap,
    float* __restrict__ z, int N)
{
  __shared__ ushort As[128 * 136];
  const int t = threadIdx.x;
  const int row0 = blockIdx.x * 128;
  stage128(h, N, row0, As, t);
  __syncthreads();
  const int lane = t & 63, w = t >> 6;
  const int wm = w >> 1, wn = w & 1;
  f32x4 acc[4][4] = {};
  mma_tile_l(As + wm * 64 * 136, Wpb + (size_t)(wn * 64) * D, D, acc, lane);
  const float alpha = ap[0];
  const int g = lane >> 4, cr = lane & 15;
#pragma unroll
  for (int n = 0; n < 4; ++n) {
    int col = wn * 64 + n * 16 + cr;
    float b = bp[col];
#pragma unroll
    for (int m = 0; m < 4; ++m)
#pragma unroll
      for (int rr = 0; rr < 4; ++rr) {
        int row = row0 + wm * 64 + m * 16 + g * 4 + rr;
        if (row < N) {
          float v = acc[m][n][rr] + b;
          z[(size_t)row * D + col] = (v >= 0.f) ? v : alpha * v;
        }
      }
  }
}

// ---------------------------------------------------------------- launch
extern "C" void kernel_launch(void* const* d_in, const int* in_sizes, int n_in,
                              void* d_out, int out_size, void* d_ws, size_t ws_size,
                              hipStream_t stream)
{
  const float* x   = (const float*)d_in[0];
  const int*   ei  = (const int*)d_in[1];
  const float* Wl  = (const float*)d_in[2];
  const float* bl  = (const float*)d_in[3];
  const float* Wr  = (const float*)d_in[4];
  const float* Wp  = (const float*)d_in[5];
  const float* bp  = (const float*)d_in[6];
  const float* ap  = (const float*)d_in[7];
  const float* Wd1 = (const float*)d_in[8];
  const float* bd1 = (const float*)d_in[9];  // cancels in BN algebra; unused
  const float* gm  = (const float*)d_in[10];
  const float* bt  = (const float*)d_in[11];
  const float* Wd2 = (const float*)d_in[12];
  const float* bd2 = (const float*)d_in[13];
  (void)bd1;

  const int N = in_sizes[0] / D;   // 100000
  const int E = in_sizes[1] / 2;   // 1600000

  float* h_out   = (float*)d_out;
  float* z_out   = h_out + (size_t)N * D;
  float* rec_out = z_out + (size_t)N * D;
  float* tgt_out = rec_out + (size_t)N * D;

  const size_t ws_need = ((size_t)3 * N + E + 4096) * 4
                       + (size_t)3 * N * D * 2 + 360448
                       + ((size_t)N + 128) * DDEC * 2 + 2048;
  const bool usews = ws_size >= ws_need;

  int *deg, *fillc, *bsum, *flag, *rowptr, *colidx;
  float *sums, *sumsq, *scale, *shift;
  ushort *xb, *hb, *aggrb, *wb;

  if (usews) {
    deg    = (int*)d_ws;                 // N
    fillc  = deg + N;                    // N
    sums   = (float*)(fillc + N);        // 512
    sumsq  = sums + 512;                 // 512   <- zero region: 2N+1024 ints
    scale  = sumsq + 512;
    shift  = scale + 512;
    bsum   = (int*)(shift + 512);        // 256
    flag   = bsum + 256;                 // 1 (+15 pad)
    rowptr = flag + 16;                  // N+1 (+pad)
    colidx = rowptr + (N + 16);          // E
    xb     = (ushort*)(((uintptr_t)(colidx + E) + 255) & ~(uintptr_t)255);
    hb     = xb + (size_t)N * D;
    aggrb  = hb + (size_t)N * D;
    wb     = aggrb + (size_t)N * D;      // 180224 (+ slack after for OOB-row reads)
  } else {
    sums   = (float*)d_ws;
    sumsq  = sums + DDEC;
    scale  = sumsq + DDEC;
    shift  = scale + DDEC;
    flag   = (int*)(shift + DDEC);
    bsum   = flag + 1;
    colidx = (int*)tgt_out;
    deg    = colidx + E;
    fillc  = deg + N;
    rowptr = fillc + N;
    xb     = (ushort*)(tgt_out + 2000000);
    wb     = (ushort*)(tgt_out + 8500000);
    aggrb  = (ushort*)z_out;
    hb     = aggrb + (size_t)N * D;
  }
  ushort* Wlb  = wb;
  ushort* Wrb  = wb + 16384;
  ushort* Wpb  = wb + 32768;
  ushort* Wd1b = wb + 49152;
  ushort* Wd2b = wb + 114688;

  if (usews) {
    // zero deg/fillc/sums/sumsq (2N+1024 ints) via kernel + detect in one launch
    int nz = 2 * N + 1024;
    int nz4 = nz / 4;
    int zblocks = (nz4 + 255) / 256;
    init_kernel<<<zblocks + 1, 256, 0, stream>>>(ei, flag, (int4*)deg, nz4, zblocks);
  } else {
    hipMemsetAsync(deg, 0, (size_t)2 * N * sizeof(int), stream);
    hipMemsetAsync(sums, 0, (size_t)2 * DDEC * sizeof(float), stream);
    detect_i64_fallback:;
    init_kernel<<<1, 256, 0, stream>>>(ei, flag, nullptr, 0, 0);
  }

  int n8 = N * (D / 8);
  int xblocks = (n8 + 255) / 256;
  int eb = (E + 255) / 256;
  prep_count_kernel<<<xblocks + 704 + eb, 256, 0, stream>>>(
      x, Wl, Wr, Wp, Wd1, Wd2, ei, xb, wb,
      usews ? tgt_out : nullptr, deg, flag, n8, xblocks, E);

  int NB = (N + 1023) / 1024;
  scan_reduce<<<NB, 256, 0, stream>>>(deg, bsum, N);
  scan_bsum<<<1, 256, 0, stream>>>(bsum, rowptr, NB, N, E);
  scan_final<<<NB, 256, 0, stream>>>(deg, bsum, rowptr, N);

  fill_csr<<<eb, 256, 0, stream>>>(ei, rowptr, fillc, colidx, flag, E);

  long long ag_threads = (long long)N * 64;
  aggregate_kernel<<<(int)((ag_threads + 255) / 256), 256, 0, stream>>>(
      rowptr, colidx, xb, aggrb, N);

  int rb = (N + 127) / 128;
  if (usews) {
    gemm_hz_dstat<<<rb, 256, 0, stream>>>(aggrb, xb, Wlb, Wrb, Wpb, Wd1b,
                                          bl, bp, ap, h_out, hb, z_out,
                                          sums, sumsq, N);
    finalize_kernel<<<2, 256, 0, stream>>>(sums, sumsq, gm, bt, scale, shift, N);
    rec_mfma<<<rb, 256, 0, stream>>>(hb, Wd1b, Wd2b, scale, shift, bd2, rec_out, N);
  } else {
    gemm_h_mfma<<<rb, 256, 0, stream>>>(aggrb, xb, Wlb, Wrb, bl, h_out, hb, N);
    dstat_mfma<<<rb, 256, 0, stream>>>(hb, Wd1b, sums, sumsq, N);
    finalize_kernel<<<2, 256, 0, stream>>>(sums, sumsq, gm, bt, scale, shift, N);
    rec_mfma_fb<<<rb, 256, 0, stream>>>(hb, Wd1b, Wd2b, scale, shift, bd2, rec_out, N);
    gemm_z_staged<<<rb, 256, 0, stream>>>(h_out, Wpb, bp, ap, z_out, N);
    hipMemcpyAsync(tgt_out, x, (size_t)N * D * sizeof(float), hipMemcpyDeviceToDevice, stream);
  }
}